// Round 8
// baseline (304.685 us; speedup 1.0000x reference)
//
#include <hip/hip_runtime.h>

// NativeSparseAttention round 8: dispatch-graph restructure — qkv3+ck/cv GEMMs
// fused into one dispatch (MFMA/VALU pipe overlap across blocks), imp chain
// collapsed 4->2 (single-pass M1, imp GEMM with inline top-2). 11 -> 8 launches.
// B=2 S=1024 D=1024 H=KV=16 HD=64 Nc=64 CB=16 SB=8 J=2 W=256

typedef __bf16 bf16;
typedef bf16 bf16x8 __attribute__((ext_vector_type(8)));
typedef float f32x4 __attribute__((ext_vector_type(4)));

constexpr int kD = 1024;
constexpr float kInv = 0.125f;  // 1/sqrt(64)

#define SWZ_IDX(row, cb) (((row) << 6) + (((cb) ^ ((row) & 7)) << 3))
#define LDV(arr, row, cb) (*(const bf16x8*)&(arr)[SWZ_IDX(row, cb)])

__device__ __forceinline__ void async_ld16(const bf16* g, bf16* l) {
  __builtin_amdgcn_global_load_lds(
      (const __attribute__((address_space(1))) unsigned int*)g,
      (__attribute__((address_space(3))) unsigned int*)l, 16, 0, 0);
}

// ---- fused prep: [0,512) cx ; [512,1536) x->bf16 ; [1536,3584) gates ;
//      [3584,7680) transpose 4 weights -> bf16 [C][R] ----
__global__ __launch_bounds__(256) void prep_all(const float* __restrict__ x, const float* __restrict__ wkc,
                                                const float* __restrict__ wvc, const float* __restrict__ Wg,
                                                const float* __restrict__ bg, const float* __restrict__ Wq,
                                                const float* __restrict__ Wk, const float* __restrict__ Wv,
                                                const float* __restrict__ Wo, float* __restrict__ cxk,
                                                float* __restrict__ cxv, bf16* __restrict__ xbf,
                                                float* __restrict__ gates, bf16* __restrict__ Wt4) {
  __shared__ float sh[32 * 33];
  int blk = blockIdx.x, tid = threadIdx.x;
  if (blk < 512) {
    int idx = blk * 256 + tid;
    int d = idx & 1023, bn = idx >> 10;
    const float* xp = x + (size_t)bn * 16 * kD + d;
    float a = 0.f, c = 0.f;
    for (int t = 0; t < 16; ++t) {
      float xv = xp[(size_t)t * kD];
      a += wkc[t] * xv;
      c += wvc[t] * xv;
    }
    cxk[idx] = a;
    cxv[idx] = c;
  } else if (blk < 1536) {
    int i = (blk - 512) * 256 + tid;
    const float4* p = (const float4*)x + (size_t)i * 2;
    float4 a = p[0], b = p[1];
    bf16x8 v;
    v[0] = (bf16)a.x; v[1] = (bf16)a.y; v[2] = (bf16)a.z; v[3] = (bf16)a.w;
    v[4] = (bf16)b.x; v[5] = (bf16)b.y; v[6] = (bf16)b.z; v[7] = (bf16)b.w;
    *(bf16x8*)&xbf[(size_t)i * 8] = v;
  } else if (blk < 3584) {
    int bs = blk - 1536;
    float (*red)[256] = (float(*)[256])sh;
    const float* xp = x + (size_t)bs * kD;
    float p0 = 0.f, p1 = 0.f, p2 = 0.f;
    for (int d = tid; d < kD; d += 256) {
      float xv = xp[d];
      p0 += xv * Wg[d * 3 + 0];
      p1 += xv * Wg[d * 3 + 1];
      p2 += xv * Wg[d * 3 + 2];
    }
    red[0][tid] = p0; red[1][tid] = p1; red[2][tid] = p2;
    __syncthreads();
    for (int off = 128; off > 0; off >>= 1) {
      if (tid < off) {
        red[0][tid] += red[0][tid + off];
        red[1][tid] += red[1][tid + off];
        red[2][tid] += red[2][tid + off];
      }
      __syncthreads();
    }
    if (tid < 3) gates[bs * 3 + tid] = 1.f / (1.f + __expf(-(red[tid][0] + bg[tid])));
  } else {
    int t4 = blk - 3584;
    int z = t4 >> 10, rem = t4 & 1023;
    const float* in = (z == 0) ? Wq : (z == 1) ? Wk : (z == 2) ? Wv : Wo;
    bf16* outp = Wt4 + (size_t)z * 1048576;
    int c0 = (rem & 31) * 32, r0 = (rem >> 5) * 32;
    float (*t)[33] = (float(*)[33])sh;
    int tx = tid & 31, ty = tid >> 5;
#pragma unroll
    for (int i = 0; i < 32; i += 8) t[ty + i][tx] = in[(size_t)(r0 + ty + i) * 1024 + c0 + tx];
    __syncthreads();
#pragma unroll
    for (int i = 0; i < 32; i += 8) outp[(size_t)(c0 + ty + i) * 1024 + r0 + tx] = (bf16)t[tx][ty + i];
  }
}

// ---- fused mid: blocks [0,256) z-fused QKV MFMA GEMM; [256,768) fp32 split-K
// ck|cv GEMM partials. Independent work co-scheduled -> MFMA+VALU pipe overlap.
__global__ __launch_bounds__(256) void mid_fused(const bf16* __restrict__ xbf, const bf16* __restrict__ Wt4,
                                                 bf16* __restrict__ qkv, const float* __restrict__ wpe,
                                                 const float* __restrict__ cxk, const float* __restrict__ cxv,
                                                 const float* __restrict__ Wk, const float* __restrict__ Wv,
                                                 float* __restrict__ part) {
  __shared__ __align__(16) char smem[40960];
  int tid = threadIdx.x;
  if (blockIdx.x < 256) {
    // ---- QKV: BM=128 BN=64 BK=64, one tile for all 3 weights ----
    bf16* As = (bf16*)smem;             // 128*64 = 16 KB
    bf16* Bs = (bf16*)(smem + 16384);   // 3*64*64 = 24 KB
    int w = tid >> 6, lane = tid & 63;
    int l8 = lane >> 3, s8 = lane & 7;
    int qd = lane >> 4, l16 = lane & 15;
    int row0 = (blockIdx.x >> 4) * 128, col0 = (blockIdx.x & 15) * 64;
    int mr = (w & 1) * 64, nc = (w >> 1) * 32;
    f32x4 acc[3][4][2] = {};
    for (int k0 = 0; k0 < 1024; k0 += 64) {
      __syncthreads();
#pragma unroll
      for (int i = 0; i < 4; ++i) {
        int row = w * 32 + i * 8 + l8;
        async_ld16(&xbf[(size_t)(row0 + row) * 1024 + k0 + (s8 ^ l8) * 8], As + w * 2048 + i * 512);
      }
#pragma unroll
      for (int i = 0; i < 6; ++i) {
        int g = w * 6 + i;
        int z = g >> 3, rg = g & 7;
        int row = rg * 8 + l8;
        async_ld16(&Wt4[(size_t)z * 1048576 + (size_t)(col0 + row) * 1024 + k0 + (s8 ^ l8) * 8],
                   Bs + z * 4096 + rg * 512);
      }
      __syncthreads();
#pragma unroll
      for (int ks = 0; ks < 2; ++ks) {
        bf16x8 af[4];
#pragma unroll
        for (int i = 0; i < 4; ++i) af[i] = LDV(As, mr + i * 16 + l16, ks * 4 + qd);
#pragma unroll
        for (int z = 0; z < 3; ++z) {
          bf16x8 bfr[2];
#pragma unroll
          for (int j = 0; j < 2; ++j) bfr[j] = LDV(Bs + z * 4096, nc + j * 16 + l16, ks * 4 + qd);
#pragma unroll
          for (int i = 0; i < 4; ++i)
#pragma unroll
            for (int j = 0; j < 2; ++j)
              acc[z][i][j] = __builtin_amdgcn_mfma_f32_16x16x32_bf16(af[i], bfr[j], acc[z][i][j], 0, 0, 0);
        }
      }
    }
#pragma unroll
    for (int z = 0; z < 3; ++z) {
      bf16* C = qkv + (size_t)z * 2097152;
#pragma unroll
      for (int i = 0; i < 4; ++i)
#pragma unroll
        for (int j = 0; j < 2; ++j)
#pragma unroll
          for (int r = 0; r < 4; ++r) {
            int rr = row0 + mr + i * 16 + qd * 4 + r;
            int cc = col0 + nc + j * 16 + l16;
            float v = acc[z][i][j][r];
            if (z) v += wpe[(rr & 15) * kD + cc];
            C[(size_t)rr * kD + cc] = (bf16)v;
          }
    }
  } else {
    // ---- ck|cv split-K fp32 partials: z<8 -> cxk@Wk, z>=8 -> cxv@Wv ----
    float (*As2)[17] = (float(*)[17])smem;            // 64x17
    float (*Bs)[68] = (float(*)[68])(smem + 4352);    // 16x68
    int t = blockIdx.x - 256;
    int z = t >> 5, rem = t & 31;
    const float* A = (z < 8) ? cxk : cxv;
    const float* Bm = (z < 8) ? Wk : Wv;
    int tm = tid >> 4, tn = tid & 15;
    int row0 = (rem >> 4) * 64, col0 = (rem & 15) * 64;
    int k0b = (z & 7) * 128;
    float acc[4][4] = {{0.f}};
    for (int k0 = k0b; k0 < k0b + 128; k0 += 16) {
#pragma unroll
      for (int i = 0; i < 4; ++i) {
        int idx = tid + i * 256;
        As2[idx >> 4][idx & 15] = A[(size_t)(row0 + (idx >> 4)) * 1024 + k0 + (idx & 15)];
        Bs[idx >> 6][idx & 63] = Bm[(size_t)(k0 + (idx >> 6)) * 1024 + col0 + (idx & 63)];
      }
      __syncthreads();
#pragma unroll
      for (int kk = 0; kk < 16; ++kk) {
        float a[4], b[4];
#pragma unroll
        for (int i = 0; i < 4; ++i) a[i] = As2[tm * 4 + i][kk];
#pragma unroll
        for (int j = 0; j < 4; ++j) b[j] = Bs[kk][tn * 4 + j];
#pragma unroll
        for (int i = 0; i < 4; ++i)
#pragma unroll
          for (int j = 0; j < 4; ++j) acc[i][j] += a[i] * b[j];
      }
      __syncthreads();
    }
    float* pp = part + (size_t)z * 131072;
#pragma unroll
    for (int i = 0; i < 4; ++i) {
      float4 v = make_float4(acc[i][0], acc[i][1], acc[i][2], acc[i][3]);
      *(float4*)&pp[(size_t)(row0 + tm * 4 + i) * 1024 + col0 + tn * 4] = v;
    }
  }
}

// ---- reduce ck|cv partials with inline cpe ----
__global__ __launch_bounds__(256) void reduce_ckcv(const float* __restrict__ part, float* __restrict__ ck,
                                                   float* __restrict__ cv, const float* __restrict__ wkc,
                                                   const float* __restrict__ wvc, const float* __restrict__ wpe) {
  int half = blockIdx.x >> 7;
  int i4 = (((blockIdx.x & 127) * 256) + threadIdx.x) * 4;
  const float* pp = part + (size_t)half * 8 * 131072;
  float4 s = *(const float4*)&pp[i4];
  for (int z = 1; z < 8; ++z) {
    float4 p = *(const float4*)&pp[(size_t)z * 131072 + i4];
    s.x += p.x; s.y += p.y; s.z += p.z; s.w += p.w;
  }
  int c = i4 & 1023;
  const float* w = half ? wvc : wkc;
  float e0 = 0.f, e1 = 0.f, e2 = 0.f, e3 = 0.f;
  for (int t = 0; t < 16; ++t) {
    float wt = w[t];
    const float* pe = wpe + t * 1024 + c;
    e0 += wt * pe[0]; e1 += wt * pe[1]; e2 += wt * pe[2]; e3 += wt * pe[3];
  }
  s.x += e0; s.y += e1; s.z += e2; s.w += e3;
  float* dst = half ? cv : ck;
  *(float4*)&dst[i4] = s;
}

// ---- M1[d][bn] = sum_k Wq[d][k]*ck[bn][k], single-pass 16x32 tiles, fp32 ----
__global__ __launch_bounds__(256) void m1_gemm(const float* __restrict__ Wq, const float* __restrict__ ck,
                                               float* __restrict__ M1) {
  __shared__ float As2[16][17];
  __shared__ float Bs2[32][17];
  int tid = threadIdx.x;
  int row0 = blockIdx.y * 16, col0 = blockIdx.x * 32;
  int row = tid >> 4, c2 = (tid & 15) * 2;
  float a0 = 0.f, a1 = 0.f;
  for (int k0 = 0; k0 < 1024; k0 += 16) {
    As2[tid >> 4][tid & 15] = Wq[(size_t)(row0 + (tid >> 4)) * 1024 + k0 + (tid & 15)];
#pragma unroll
    for (int i = 0; i < 2; ++i) {
      int idx = tid + i * 256;
      Bs2[idx >> 4][idx & 15] = ck[(size_t)(col0 + (idx >> 4)) * 1024 + k0 + (idx & 15)];
    }
    __syncthreads();
#pragma unroll
    for (int kk = 0; kk < 16; ++kk) {
      float a = As2[row][kk];
      a0 += a * Bs2[c2][kk];
      a1 += a * Bs2[c2 + 1][kk];
    }
    __syncthreads();
  }
  M1[(size_t)(row0 + row) * 128 + col0 + c2] = a0;
  M1[(size_t)(row0 + row) * 128 + col0 + c2 + 1] = a1;
}

// ---- imp rows (8 per block) + inline top-2: imp = x @ M1[:, batch cols] ----
__global__ __launch_bounds__(256) void imp_topk(const float* __restrict__ x, const float* __restrict__ M1,
                                                int* __restrict__ tk) {
  __shared__ float As2[8][17];
  __shared__ float Bs[16][68];
  __shared__ float impS[8][65];
  int tid = threadIdx.x;
  int rows0 = blockIdx.x * 8;                 // bs rows [rows0, rows0+8)
  int colbase = (rows0 >> 10) * 64;           // batch column block
  int row = tid >> 5, c2 = (tid & 31) * 2;
  float a0 = 0.f, a1 = 0.f;
  for (int k0 = 0; k0 < 1024; k0 += 16) {
    if (tid < 128) As2[tid >> 4][tid & 15] = x[(size_t)(rows0 + (tid >> 4)) * 1024 + k0 + (tid & 15)];
#pragma unroll
    for (int i = 0; i < 4; ++i) {
      int idx = tid + i * 256;
      Bs[idx >> 6][idx & 63] = M1[(size_t)(k0 + (idx >> 6)) * 128 + colbase + (idx & 63)];
    }
    __syncthreads();
#pragma unroll
    for (int kk = 0; kk < 16; ++kk) {
      float a = As2[row][kk];
      a0 += a * Bs[kk][c2];
      a1 += a * Bs[kk][c2 + 1];
    }
    __syncthreads();
  }
  impS[row][c2] = a0;
  impS[row][c2 + 1] = a1;
  __syncthreads();
  if (tid < 8) {  // serial top-2 per row; ties -> lower index (lax.top_k)
    float v1 = -3.0e38f, v2 = -3.0e38f;
    int i1 = 0, i2 = 0;
    for (int n = 0; n < 64; ++n) {
      float v = impS[tid][n];
      if (v > v1) { v2 = v1; i2 = i1; v1 = v; i1 = n; }
      else if (v > v2) { v2 = v; i2 = n; }
    }
    int bs = rows0 + tid;
    tk[bs * 2] = i1;
    tk[bs * 2 + 1] = i2;
  }
}

// ---- staging helpers (fp32 ck/cv -> swizzled bf16 LDS) ----
__device__ inline void stage_rows_bf16(const float* __restrict__ src, size_t pitch,
                                       bf16* __restrict__ dst, int tid) {
  int r = tid >> 2, qq = tid & 3;
  const float4* sp = (const float4*)(src + (size_t)r * pitch) + qq * 4;
  float4 f0 = sp[0], f1 = sp[1], f2 = sp[2], f3 = sp[3];
  bf16x8 lo, hi;
  lo[0] = (bf16)f0.x; lo[1] = (bf16)f0.y; lo[2] = (bf16)f0.z; lo[3] = (bf16)f0.w;
  lo[4] = (bf16)f1.x; lo[5] = (bf16)f1.y; lo[6] = (bf16)f1.z; lo[7] = (bf16)f1.w;
  hi[0] = (bf16)f2.x; hi[1] = (bf16)f2.y; hi[2] = (bf16)f2.z; hi[3] = (bf16)f2.w;
  hi[4] = (bf16)f3.x; hi[5] = (bf16)f3.y; hi[6] = (bf16)f3.z; hi[7] = (bf16)f3.w;
  int cb = qq * 2;
  *(bf16x8*)&dst[SWZ_IDX(r, cb)]     = lo;
  *(bf16x8*)&dst[SWZ_IDX(r, cb + 1)] = hi;
}

__device__ inline void stage_cols_bf16(const float* __restrict__ src, size_t pitch,
                                       bf16* __restrict__ dst, int tid) {
  int lane = tid & 63, w = tid >> 6;
  const float4* sp = (const float4*)(src + (size_t)lane * pitch + w * 16);
  float4 f[4];
  f[0] = sp[0]; f[1] = sp[1]; f[2] = sp[2]; f[3] = sp[3];
  const float* ff = (const float*)f;
#pragma unroll
  for (int i = 0; i < 16; ++i) {
    int d = w * 16 + i;
    dst[(d << 6) + ((((lane >> 3) ^ (d & 7))) << 3) + (lane & 7)] = (bf16)ff[i];
  }
}

// ---- fused comp + window MFMA flash attention, double-buffered K/V ----
__global__ __launch_bounds__(256) void attn_mfma(const bf16* __restrict__ qbf, const bf16* __restrict__ kbf,
                                                 const bf16* __restrict__ vbf, const float* __restrict__ ck,
                                                 const float* __restrict__ cv, const float* __restrict__ gat,
                                                 const float* __restrict__ selp, bf16* __restrict__ accbf) {
  __shared__ bf16 Qs[4096];
  __shared__ bf16 Kb[2][4096];
  __shared__ bf16 Vb[2][4096];
  __shared__ bf16 Ps[4096];
  int tid = threadIdx.x, w = tid >> 6, lane = tid & 63;
  int l8 = lane >> 3, s8 = lane & 7;
  int qd = lane >> 4, l16 = lane & 15;
  int s0 = blockIdx.x * 64, h = blockIdx.y, b = blockIdx.z;
  bf16* Pw = Ps + w * 1024;

  const bf16* qsrc = qbf + ((size_t)(b * 1024 + s0)) * kD + h * 64;
#pragma unroll
  for (int i = 0; i < 2; ++i) {
    int row = w * 16 + i * 8 + l8;
    async_ld16(&qsrc[(size_t)row * kD + (s8 ^ l8) * 8], Qs + w * 1024 + i * 512);
  }
  stage_rows_bf16(ck + ((size_t)(b * 64)) * kD + h * 64, kD, Kb[0], tid);
  stage_cols_bf16(cv + ((size_t)(b * 64)) * kD + h * 64, kD, Vb[0], tid);
  __syncthreads();

  int kb0 = s0 - 256; if (kb0 < 0) kb0 = 0;
  int nck = (s0 + 64 - kb0) >> 6;

  bf16x8 pv0, pv1;
  {
    const bf16* ksrc = kbf + ((size_t)(b * 1024 + kb0)) * kD + h * 64;
#pragma unroll
    for (int i = 0; i < 2; ++i) {
      int row = w * 16 + i * 8 + l8;
      async_ld16(&ksrc[(size_t)row * kD + (s8 ^ l8) * 8], Kb[1] + w * 1024 + i * 512);
    }
    const bf16* vsrc = vbf + ((size_t)(b * 1024 + kb0 + lane)) * kD + h * 64 + w * 16;
    pv0 = *(const bf16x8*)vsrc;
    pv1 = *(const bf16x8*)(vsrc + 8);
  }

  f32x4 oc[4] = {};
  float lc[4];
  {
    f32x4 sacc[4] = {};
#pragma unroll
    for (int ks = 0; ks < 2; ++ks) {
      bf16x8 aq = LDV(Qs, w * 16 + l16, qd + 4 * ks);
#pragma unroll
      for (int j = 0; j < 4; ++j)
        sacc[j] = __builtin_amdgcn_mfma_f32_16x16x32_bf16(aq, LDV(Kb[0], 16 * j + l16, qd + 4 * ks), sacc[j], 0, 0, 0);
    }
    {
      bf16* Vt = Vb[1];
#pragma unroll
      for (int i = 0; i < 8; ++i) { int d = w * 16 + i;     Vt[(d << 6) + ((l8 ^ (d & 7)) << 3) + s8] = pv0[i]; }
#pragma unroll
      for (int i = 0; i < 8; ++i) { int d = w * 16 + 8 + i; Vt[(d << 6) + ((l8 ^ (d & 7)) << 3) + s8] = pv1[i]; }
    }
#pragma unroll
    for (int j = 0; j < 4; ++j)
#pragma unroll
      for (int r = 0; r < 4; ++r) sacc[j][r] *= kInv;
#pragma unroll
    for (int r = 0; r < 4; ++r) {
      float mx = sacc[0][r];
#pragma unroll
      for (int j = 1; j < 4; ++j) mx = fmaxf(mx, sacc[j][r]);
#pragma unroll
      for (int off = 8; off; off >>= 1) mx = fmaxf(mx, __shfl_xor(mx, off));
      int qrow = qd * 4 + r;
      float rs = 0.f;
#pragma unroll
      for (int j = 0; j < 4; ++j) {
        float e = __expf(sacc[j][r] - mx);
        int col = l16 + 16 * j;
        Pw[(qrow << 6) + ((((col >> 3) ^ (qrow & 7))) << 3) + (col & 7)] = (bf16)e;
        rs += e;
      }
#pragma unroll
      for (int off = 8; off; off >>= 1) rs += __shfl_xor(rs, off);
      lc[r] = rs;
    }
#pragma unroll
    for (int ks = 0; ks < 2; ++ks) {
      bf16x8 ap = LDV(Pw, l16, qd + 4 * ks);
#pragma unroll
      for (int j = 0; j < 4; ++j)
        oc[j] = __builtin_amdgcn_mfma_f32_16x16x32_bf16(ap, LDV(Vb[0], 16 * j + l16, qd + 4 * ks), oc[j], 0, 0, 0);
    }
  }

  f32x4 ow[4] = {};
  float mw[4], lw[4];
#pragma unroll
  for (int r = 0; r < 4; ++r) { mw[r] = -1e30f; lw[r] = 0.f; }
  for (int c = 0; c < nck; ++c) {
    int cur = (c & 1) ^ 1, oth = c & 1;
    int kbase = kb0 + c * 64;
    __syncthreads();
    if (c + 1 < nck) {
      const bf16* ksrc = kbf + ((size_t)(b * 1024 + kbase + 64)) * kD + h * 64;
#pragma unroll
      for (int i = 0; i < 2; ++i) {
        int row = w * 16 + i * 8 + l8;
        async_ld16(&ksrc[(size_t)row * kD + (s8 ^ l8) * 8], Kb[oth] + w * 1024 + i * 512);
      }
      const bf16* vsrc = vbf + ((size_t)(b * 1024 + kbase + 64 + lane)) * kD + h * 64 + w * 16;
      pv0 = *(const bf16x8*)vsrc;
      pv1 = *(const bf16x8*)(vsrc + 8);
    }
    f32x4 sacc[4] = {};
#pragma unroll
    for (int ks = 0; ks < 2; ++ks) {
      bf16x8 aq = LDV(Qs, w * 16 + l16, qd + 4 * ks);
#pragma unroll
      for (int j = 0; j < 4; ++j)
        sacc[j] = __builtin_amdgcn_mfma_f32_16x16x32_bf16(aq, LDV(Kb[cur], 16 * j + l16, qd + 4 * ks), sacc[j], 0, 0, 0);
    }
    if (c + 1 < nck) {
      bf16* Vt = Vb[oth];
#pragma unroll
      for (int i = 0; i < 8; ++i) { int d = w * 16 + i;     Vt[(d << 6) + ((l8 ^ (d & 7)) << 3) + s8] = pv0[i]; }
#pragma unroll
      for (int i = 0; i < 8; ++i) { int d = w * 16 + 8 + i; Vt[(d << 6) + ((l8 ^ (d & 7)) << 3) + s8] = pv1[i]; }
    }
#pragma unroll
    for (int j = 0; j < 4; ++j)
#pragma unroll
      for (int r = 0; r < 4; ++r) {
        int key = kbase + 16 * j + l16;
        int sq = s0 + w * 16 + qd * 4 + r;
        float sc = sacc[j][r] * kInv;
        sacc[j][r] = (key <= sq && sq - key <= 256) ? sc : -1e30f;
      }
#pragma unroll
    for (int r = 0; r < 4; ++r) {
      float mx = sacc[0][r];
#pragma unroll
      for (int j = 1; j < 4; ++j) mx = fmaxf(mx, sacc[j][r]);
#pragma unroll
      for (int off = 8; off; off >>= 1) mx = fmaxf(mx, __shfl_xor(mx, off));
      float mn = fmaxf(mw[r], mx);
      float alpha = __expf(mw[r] - mn);
      mw[r] = mn;
      int qrow = qd * 4 + r;
      float rs = 0.f;
#pragma unroll
      for (int j = 0; j < 4; ++j) {
        float e = __expf(sacc[j][r] - mn);
        int col = l16 + 16 * j;
        Pw[(qrow << 6) + ((((col >> 3) ^ (qrow & 7))) << 3) + (col & 7)] = (bf16)e;
        rs += e;
      }
#pragma unroll
      for (int off = 8; off; off >>= 1) rs += __shfl_xor(rs, off);
      lw[r] = lw[r] * alpha + rs;
#pragma unroll
      for (int j = 0; j < 4; ++j) ow[j][r] *= alpha;
    }
#pragma unroll
    for (int ks = 0; ks < 2; ++ks) {
      bf16x8 ap = LDV(Pw, l16, qd + 4 * ks);
#pragma unroll
      for (int j = 0; j < 4; ++j)
        ow[j] = __builtin_amdgcn_mfma_f32_16x16x32_bf16(ap, LDV(Vb[cur], 16 * j + l16, qd + 4 * ks), ow[j], 0, 0, 0);
    }
  }

#pragma unroll
  for (int r = 0; r < 4; ++r) {
    int sq = s0 + w * 16 + qd * 4 + r;
    size_t row = (size_t)b * 1024 + sq;
    float g0 = gat[row * 3 + 0], g2 = gat[row * 3 + 2];
    float c0 = g0 / lc[r], c2 = g2 / lw[r];
#pragma unroll
    for (int j = 0; j < 4; ++j) {
      size_t off = row * kD + h * 64 + 16 * j + l16;
      accbf[off] = (bf16)(oc[j][r] * c0 + ow[j][r] * c2 + selp[off]);
    }
  }
}

// ---- selected attention: writes selp = g1*out_sel ----
__global__ __launch_bounds__(256) void sel_attn2(const bf16* __restrict__ qbf, const bf16* __restrict__ kbf,
                                                 const bf16* __restrict__ vbf, const int* __restrict__ tk,
                                                 const float* __restrict__ gat, float* __restrict__ selp) {
  int wid = threadIdx.x >> 6, lane = threadIdx.x & 63;
  int g = blockIdx.x * 4 + wid;
  int h = g & 15, bs = g >> 4, b = bs >> 10, s = bs & 1023;
  __shared__ float qs[4][64];
  qs[wid][lane] = (float)qbf[(size_t)bs * kD + h * 64 + lane];
  __syncthreads();
  int m = lane & 15, dg = lane >> 4;
  int blk = tk[((size_t)(m >> 3) * 1024 + s) * 2 + b];
  int tok = (m >> 3) * 1024 + blk * 16 + (m & 7);
  const bf16* kp = kbf + (size_t)tok * kD + h * 64 + dg * 16;
  bf16x8 k0 = *(const bf16x8*)kp;
  bf16x8 k1 = *(const bf16x8*)(kp + 8);
  float sc = 0.f;
#pragma unroll
  for (int i = 0; i < 8; ++i) sc += (float)k0[i] * qs[wid][dg * 16 + i];
#pragma unroll
  for (int i = 0; i < 8; ++i) sc += (float)k1[i] * qs[wid][dg * 16 + 8 + i];
  sc += __shfl_xor(sc, 16);
  sc += __shfl_xor(sc, 32);
  sc *= kInv;
  float mx = sc;
#pragma unroll
  for (int off = 8; off; off >>= 1) mx = fmaxf(mx, __shfl_xor(mx, off));
  float e = __expf(sc - mx);
  float ss = e;
#pragma unroll
  for (int off = 8; off; off >>= 1) ss += __shfl_xor(ss, off);
  float p = e / ss;
  const bf16* vb = vbf + h * 64 + lane;
  float o = 0.f;
#pragma unroll
  for (int mi = 0; mi < 16; ++mi) {
    int tm = __shfl(tok, mi);
    float pm = __shfl(p, mi);
    o += pm * (float)vb[(size_t)tm * kD];
  }
  selp[(size_t)bs * kD + h * 64 + lane] = gat[bs * 3 + 1] * o;
}

// ---- bf16 MFMA GEMM core (gemm_out) ----
__device__ __forceinline__ void gemm_core(const bf16* __restrict__ A, const bf16* __restrict__ Bt,
                                          int K, int row0, int col0, bf16* As, bf16* Bs,
                                          int tid, f32x4 (&acc)[4][2]) {
  int w = tid >> 6, lane = tid & 63;
  int l8 = lane >> 3, s8 = lane & 7;
  int qd = lane >> 4, l16 = lane & 15;
  int mr = (w & 1) * 64, nc = (w >> 1) * 32;
  for (int k0 = 0; k0 < K; k0 += 64) {
    __syncthreads();
#pragma unroll
    for (int i = 0; i < 4; ++i) {
      int row = w * 32 + i * 8 + l8;
      async_ld16(&A[(size_t)(row0 + row) * K + k0 + (s8 ^ l8) * 8], As + w * 2048 + i * 512);
    }
#pragma unroll
    for (int i = 0; i < 2; ++i) {
      int row = w * 16 + i * 8 + l8;
      async_ld16(&Bt[(size_t)(col0 + row) * K + k0 + (s8 ^ l8) * 8], Bs + w * 1024 + i * 512);
    }
    __syncthreads();
#pragma unroll
    for (int ks = 0; ks < 2; ++ks) {
      bf16x8 af[4], bfr[2];
#pragma unroll
      for (int i = 0; i < 4; ++i) af[i] = LDV(As, mr + i * 16 + l16, ks * 4 + qd);
#pragma unroll
      for (int j = 0; j < 2; ++j) bfr[j] = LDV(Bs, nc + j * 16 + l16, ks * 4 + qd);
#pragma unroll
      for (int i = 0; i < 4; ++i)
#pragma unroll
        for (int j = 0; j < 2; ++j)
          acc[i][j] = __builtin_amdgcn_mfma_f32_16x16x32_bf16(af[i], bfr[j], acc[i][j], 0, 0, 0);
    }
  }
}

// ---- out = accbf@Wo + bo, fp32 out ----
__global__ __launch_bounds__(256) void gemm_out(const bf16* __restrict__ accbf, const bf16* __restrict__ Wot,
                                                float* __restrict__ out, const float* __restrict__ bo) {
  __shared__ bf16 As[128 * 64];
  __shared__ bf16 Bs[64 * 64];
  int tid = threadIdx.x;
  int row0 = blockIdx.y * 128, col0 = blockIdx.x * 64;
  f32x4 acc[4][2] = {};
  gemm_core(accbf, Wot, 1024, row0, col0, As, Bs, tid, acc);
  int w = tid >> 6, lane = tid & 63, qd = lane >> 4, l16 = lane & 15;
  int mr = (w & 1) * 64, nc = (w >> 1) * 32;
#pragma unroll
  for (int i = 0; i < 4; ++i)
#pragma unroll
    for (int j = 0; j < 2; ++j)
#pragma unroll
      for (int r = 0; r < 4; ++r) {
        int rr = row0 + mr + i * 16 + qd * 4 + r;
        int cc = col0 + nc + j * 16 + l16;
        out[(size_t)rr * kD + cc] = acc[i][j][r] + bo[cc];
      }
}

extern "C" void kernel_launch(void* const* d_in, const int* in_sizes, int n_in,
                              void* d_out, int out_size, void* d_ws, size_t ws_size,
                              hipStream_t stream) {
  const float* x   = (const float*)d_in[0];
  const float* Wq  = (const float*)d_in[1];
  const float* Wk  = (const float*)d_in[2];
  const float* Wv  = (const float*)d_in[3];
  const float* Wo  = (const float*)d_in[4];
  const float* bo  = (const float*)d_in[5];
  const float* Wg  = (const float*)d_in[6];
  const float* bg  = (const float*)d_in[7];
  const float* wkc = (const float*)d_in[8];
  const float* wvc = (const float*)d_in[9];
  const float* wpe = (const float*)d_in[10];
  float* out = (float*)d_out;

  float* ws    = (float*)d_ws;
  bf16*  qkvbf = (bf16*)ws;                    // 3 x 2097152 bf16
  float* accb  = ws + 3145728;                 // 2097152 (sel partial, fp32)
  float* ck    = accb + 2097152;               // 131072
  float* cv    = ck + 131072;
  float* cxk   = cv + 131072;
  float* cxv   = cxk + 131072;
  float* M1    = cxv + 131072;                 // [1024][128]
  float* gat   = M1 + 131072;                  // 6144
  int*   tk    = (int*)(gat + 6144);           // 4096 ints
  bf16*  xbf   = (bf16*)(gat + 6144 + 4096);   // 2097152 bf16
  bf16*  Wt4   = (bf16*)((float*)xbf + 1048576);   // 4 x 1048576 bf16
  bf16*  accbf = (bf16*)((float*)Wt4 + 2097152);   // 2097152 bf16
  float* skbuf = (float*)accbf + 1048576;      // 16 x 131072 (ck|cv partials)
  const bf16* qbf = qkvbf;
  const bf16* kbf = qkvbf + 2097152;
  const bf16* vbf = qkvbf + 2 * 2097152;

  prep_all<<<7680, 256, 0, stream>>>(x, wkc, wvc, Wg, bg, Wq, Wk, Wv, Wo, cxk, cxv, xbf, gat, Wt4);

  mid_fused<<<768, 256, 0, stream>>>(xbf, Wt4, qkvbf, wpe, cxk, cxv, Wk, Wv, skbuf);
  reduce_ckcv<<<256, 256, 0, stream>>>(skbuf, ck, cv, wkc, wvc, wpe);

  m1_gemm<<<dim3(4, 64), 256, 0, stream>>>(Wq, ck, M1);
  imp_topk<<<256, 256, 0, stream>>>(x, M1, tk);

  sel_attn2<<<8192, 256, 0, stream>>>(qbf, kbf, vbf, tk, gat, accb);
  attn_mfma<<<dim3(16, 16, 2), 256, 0, stream>>>(qbf, kbf, vbf, ck, cv, gat, accb, accbf);

  gemm_out<<<dim3(16, 16), 256, 0, stream>>>(accbf, Wt4 + (size_t)3 * 1048576, out, bo);
}

// Round 9
// 224.550 us; speedup vs baseline: 1.3569x; 1.3569x over previous
//
#include <hip/hip_runtime.h>

// NativeSparseAttention round 9: revert round-8's imp-chain fusion (m1_gemm /
// imp_topk were latency-bound: 60 µs + ~30 µs vs 15 µs for the split-K chain).
// Keep mid_fused (qkv3 + ck/cv partials in one dispatch) and all round-7 wins.
// B=2 S=1024 D=1024 H=KV=16 HD=64 Nc=64 CB=16 SB=8 J=2 W=256

typedef __bf16 bf16;
typedef bf16 bf16x8 __attribute__((ext_vector_type(8)));
typedef float f32x4 __attribute__((ext_vector_type(4)));

constexpr int kD = 1024;
constexpr float kInv = 0.125f;  // 1/sqrt(64)

#define SWZ_IDX(row, cb) (((row) << 6) + (((cb) ^ ((row) & 7)) << 3))
#define LDV(arr, row, cb) (*(const bf16x8*)&(arr)[SWZ_IDX(row, cb)])

__device__ __forceinline__ void async_ld16(const bf16* g, bf16* l) {
  __builtin_amdgcn_global_load_lds(
      (const __attribute__((address_space(1))) unsigned int*)g,
      (__attribute__((address_space(3))) unsigned int*)l, 16, 0, 0);
}

// ---- fused prep: [0,512) cx ; [512,1536) x->bf16 ; [1536,3584) gates ;
//      [3584,7680) transpose 4 weights -> bf16 [C][R] ----
__global__ __launch_bounds__(256) void prep_all(const float* __restrict__ x, const float* __restrict__ wkc,
                                                const float* __restrict__ wvc, const float* __restrict__ Wg,
                                                const float* __restrict__ bg, const float* __restrict__ Wq,
                                                const float* __restrict__ Wk, const float* __restrict__ Wv,
                                                const float* __restrict__ Wo, float* __restrict__ cxk,
                                                float* __restrict__ cxv, bf16* __restrict__ xbf,
                                                float* __restrict__ gates, bf16* __restrict__ Wt4) {
  __shared__ float sh[32 * 33];
  int blk = blockIdx.x, tid = threadIdx.x;
  if (blk < 512) {
    int idx = blk * 256 + tid;
    int d = idx & 1023, bn = idx >> 10;
    const float* xp = x + (size_t)bn * 16 * kD + d;
    float a = 0.f, c = 0.f;
    for (int t = 0; t < 16; ++t) {
      float xv = xp[(size_t)t * kD];
      a += wkc[t] * xv;
      c += wvc[t] * xv;
    }
    cxk[idx] = a;
    cxv[idx] = c;
  } else if (blk < 1536) {
    int i = (blk - 512) * 256 + tid;
    const float4* p = (const float4*)x + (size_t)i * 2;
    float4 a = p[0], b = p[1];
    bf16x8 v;
    v[0] = (bf16)a.x; v[1] = (bf16)a.y; v[2] = (bf16)a.z; v[3] = (bf16)a.w;
    v[4] = (bf16)b.x; v[5] = (bf16)b.y; v[6] = (bf16)b.z; v[7] = (bf16)b.w;
    *(bf16x8*)&xbf[(size_t)i * 8] = v;
  } else if (blk < 3584) {
    int bs = blk - 1536;
    float (*red)[256] = (float(*)[256])sh;
    const float* xp = x + (size_t)bs * kD;
    float p0 = 0.f, p1 = 0.f, p2 = 0.f;
    for (int d = tid; d < kD; d += 256) {
      float xv = xp[d];
      p0 += xv * Wg[d * 3 + 0];
      p1 += xv * Wg[d * 3 + 1];
      p2 += xv * Wg[d * 3 + 2];
    }
    red[0][tid] = p0; red[1][tid] = p1; red[2][tid] = p2;
    __syncthreads();
    for (int off = 128; off > 0; off >>= 1) {
      if (tid < off) {
        red[0][tid] += red[0][tid + off];
        red[1][tid] += red[1][tid + off];
        red[2][tid] += red[2][tid + off];
      }
      __syncthreads();
    }
    if (tid < 3) gates[bs * 3 + tid] = 1.f / (1.f + __expf(-(red[tid][0] + bg[tid])));
  } else {
    int t4 = blk - 3584;
    int z = t4 >> 10, rem = t4 & 1023;
    const float* in = (z == 0) ? Wq : (z == 1) ? Wk : (z == 2) ? Wv : Wo;
    bf16* outp = Wt4 + (size_t)z * 1048576;
    int c0 = (rem & 31) * 32, r0 = (rem >> 5) * 32;
    float (*t)[33] = (float(*)[33])sh;
    int tx = tid & 31, ty = tid >> 5;
#pragma unroll
    for (int i = 0; i < 32; i += 8) t[ty + i][tx] = in[(size_t)(r0 + ty + i) * 1024 + c0 + tx];
    __syncthreads();
#pragma unroll
    for (int i = 0; i < 32; i += 8) outp[(size_t)(c0 + ty + i) * 1024 + r0 + tx] = (bf16)t[tx][ty + i];
  }
}

// ---- fused mid: blocks [0,256) z-fused QKV MFMA GEMM; [256,768) fp32 split-K
// ck|cv GEMM partials. Independent work co-scheduled -> MFMA+VALU pipe overlap.
__global__ __launch_bounds__(256) void mid_fused(const bf16* __restrict__ xbf, const bf16* __restrict__ Wt4,
                                                 bf16* __restrict__ qkv, const float* __restrict__ wpe,
                                                 const float* __restrict__ cxk, const float* __restrict__ cxv,
                                                 const float* __restrict__ Wk, const float* __restrict__ Wv,
                                                 float* __restrict__ part) {
  __shared__ __align__(16) char smem[40960];
  int tid = threadIdx.x;
  if (blockIdx.x < 256) {
    bf16* As = (bf16*)smem;
    bf16* Bs = (bf16*)(smem + 16384);
    int w = tid >> 6, lane = tid & 63;
    int l8 = lane >> 3, s8 = lane & 7;
    int qd = lane >> 4, l16 = lane & 15;
    int row0 = (blockIdx.x >> 4) * 128, col0 = (blockIdx.x & 15) * 64;
    int mr = (w & 1) * 64, nc = (w >> 1) * 32;
    f32x4 acc[3][4][2] = {};
    for (int k0 = 0; k0 < 1024; k0 += 64) {
      __syncthreads();
#pragma unroll
      for (int i = 0; i < 4; ++i) {
        int row = w * 32 + i * 8 + l8;
        async_ld16(&xbf[(size_t)(row0 + row) * 1024 + k0 + (s8 ^ l8) * 8], As + w * 2048 + i * 512);
      }
#pragma unroll
      for (int i = 0; i < 6; ++i) {
        int g = w * 6 + i;
        int z = g >> 3, rg = g & 7;
        int row = rg * 8 + l8;
        async_ld16(&Wt4[(size_t)z * 1048576 + (size_t)(col0 + row) * 1024 + k0 + (s8 ^ l8) * 8],
                   Bs + z * 4096 + rg * 512);
      }
      __syncthreads();
#pragma unroll
      for (int ks = 0; ks < 2; ++ks) {
        bf16x8 af[4];
#pragma unroll
        for (int i = 0; i < 4; ++i) af[i] = LDV(As, mr + i * 16 + l16, ks * 4 + qd);
#pragma unroll
        for (int z = 0; z < 3; ++z) {
          bf16x8 bfr[2];
#pragma unroll
          for (int j = 0; j < 2; ++j) bfr[j] = LDV(Bs + z * 4096, nc + j * 16 + l16, ks * 4 + qd);
#pragma unroll
          for (int i = 0; i < 4; ++i)
#pragma unroll
            for (int j = 0; j < 2; ++j)
              acc[z][i][j] = __builtin_amdgcn_mfma_f32_16x16x32_bf16(af[i], bfr[j], acc[z][i][j], 0, 0, 0);
        }
      }
    }
#pragma unroll
    for (int z = 0; z < 3; ++z) {
      bf16* C = qkv + (size_t)z * 2097152;
#pragma unroll
      for (int i = 0; i < 4; ++i)
#pragma unroll
        for (int j = 0; j < 2; ++j)
#pragma unroll
          for (int r = 0; r < 4; ++r) {
            int rr = row0 + mr + i * 16 + qd * 4 + r;
            int cc = col0 + nc + j * 16 + l16;
            float v = acc[z][i][j][r];
            if (z) v += wpe[(rr & 15) * kD + cc];
            C[(size_t)rr * kD + cc] = (bf16)v;
          }
    }
  } else {
    float (*As2)[17] = (float(*)[17])smem;
    float (*Bs)[68] = (float(*)[68])(smem + 4352);
    int t = blockIdx.x - 256;
    int z = t >> 5, rem = t & 31;
    const float* A = (z < 8) ? cxk : cxv;
    const float* Bm = (z < 8) ? Wk : Wv;
    int tm = tid >> 4, tn = tid & 15;
    int row0 = (rem >> 4) * 64, col0 = (rem & 15) * 64;
    int k0b = (z & 7) * 128;
    float acc[4][4] = {{0.f}};
    for (int k0 = k0b; k0 < k0b + 128; k0 += 16) {
#pragma unroll
      for (int i = 0; i < 4; ++i) {
        int idx = tid + i * 256;
        As2[idx >> 4][idx & 15] = A[(size_t)(row0 + (idx >> 4)) * 1024 + k0 + (idx & 15)];
        Bs[idx >> 6][idx & 63] = Bm[(size_t)(k0 + (idx >> 6)) * 1024 + col0 + (idx & 63)];
      }
      __syncthreads();
#pragma unroll
      for (int kk = 0; kk < 16; ++kk) {
        float a[4], b[4];
#pragma unroll
        for (int i = 0; i < 4; ++i) a[i] = As2[tm * 4 + i][kk];
#pragma unroll
        for (int j = 0; j < 4; ++j) b[j] = Bs[kk][tn * 4 + j];
#pragma unroll
        for (int i = 0; i < 4; ++i)
#pragma unroll
          for (int j = 0; j < 4; ++j) acc[i][j] += a[i] * b[j];
      }
      __syncthreads();
    }
    float* pp = part + (size_t)z * 131072;
#pragma unroll
    for (int i = 0; i < 4; ++i) {
      float4 v = make_float4(acc[i][0], acc[i][1], acc[i][2], acc[i][3]);
      *(float4*)&pp[(size_t)(row0 + tm * 4 + i) * 1024 + col0 + tn * 4] = v;
    }
  }
}

// ---- reduce ck|cv partials with inline cpe ----
__global__ __launch_bounds__(256) void reduce_ckcv(const float* __restrict__ part, float* __restrict__ ck,
                                                   float* __restrict__ cv, const float* __restrict__ wkc,
                                                   const float* __restrict__ wvc, const float* __restrict__ wpe) {
  int half = blockIdx.x >> 7;
  int i4 = (((blockIdx.x & 127) * 256) + threadIdx.x) * 4;
  const float* pp = part + (size_t)half * 8 * 131072;
  float4 s = *(const float4*)&pp[i4];
  for (int z = 1; z < 8; ++z) {
    float4 p = *(const float4*)&pp[(size_t)z * 131072 + i4];
    s.x += p.x; s.y += p.y; s.z += p.z; s.w += p.w;
  }
  int c = i4 & 1023;
  const float* w = half ? wvc : wkc;
  float e0 = 0.f, e1 = 0.f, e2 = 0.f, e3 = 0.f;
  for (int t = 0; t < 16; ++t) {
    float wt = w[t];
    const float* pe = wpe + t * 1024 + c;
    e0 += wt * pe[0]; e1 += wt * pe[1]; e2 += wt * pe[2]; e3 += wt * pe[3];
  }
  s.x += e0; s.y += e1; s.z += e2; s.w += e3;
  float* dst = half ? cv : ck;
  *(float4*)&dst[i4] = s;
}

// ---- split-K fp32 NT GEMM: M1 partials (imp path, fp32-exact) ----
__global__ __launch_bounds__(256) void sgemm_nt_sk(const float* __restrict__ A, const float* __restrict__ Bt,
                                                   float* __restrict__ part, int M, int N, int K, int KC) {
  __shared__ float As2[64][17];
  __shared__ float Bs2[64][17];
  int tid = threadIdx.x;
  int tm = tid >> 4, tn = tid & 15;
  int row0 = blockIdx.y * 64, col0 = blockIdx.x * 64;
  int k0b = blockIdx.z * KC;
  float acc[4][4] = {{0.f}};
  for (int k0 = k0b; k0 < k0b + KC; k0 += 16) {
#pragma unroll
    for (int i = 0; i < 4; ++i) {
      int idx = tid + i * 256;
      As2[idx >> 4][idx & 15] = A[(size_t)(row0 + (idx >> 4)) * K + k0 + (idx & 15)];
      Bs2[idx >> 4][idx & 15] = Bt[(size_t)(col0 + (idx >> 4)) * K + k0 + (idx & 15)];
    }
    __syncthreads();
#pragma unroll
    for (int kk = 0; kk < 16; ++kk) {
      float a[4], b[4];
#pragma unroll
      for (int i = 0; i < 4; ++i) a[i] = As2[tm * 4 + i][kk];
#pragma unroll
      for (int j = 0; j < 4; ++j) b[j] = Bs2[tn * 4 + j][kk];
#pragma unroll
      for (int i = 0; i < 4; ++i)
#pragma unroll
        for (int j = 0; j < 4; ++j) acc[i][j] += a[i] * b[j];
    }
    __syncthreads();
  }
  float* pp = part + (size_t)blockIdx.z * M * N;
#pragma unroll
  for (int i = 0; i < 4; ++i) {
    float4 v = make_float4(acc[i][0], acc[i][1], acc[i][2], acc[i][3]);
    *(float4*)&pp[(size_t)(row0 + tm * 4 + i) * N + col0 + tn * 4] = v;
  }
}

// ---- generic split-K reduce (M1) ----
__global__ __launch_bounds__(256) void reduce_sk(const float* __restrict__ part, float* __restrict__ C,
                                                 int total, int SK) {
  int i4 = (blockIdx.x * 256 + threadIdx.x) * 4;
  float4 s = *(const float4*)&part[i4];
  for (int z = 1; z < SK; ++z) {
    float4 p = *(const float4*)&part[(size_t)z * total + i4];
    s.x += p.x; s.y += p.y; s.z += p.z; s.w += p.w;
  }
  *(float4*)&C[i4] = s;
}

// ---- split-K imp partials ----
__global__ __launch_bounds__(256) void imp_sk(const float* __restrict__ A, const float* __restrict__ M1,
                                              float* __restrict__ part, int KC) {
  __shared__ float As2[64][17];
  __shared__ float Bs[16][68];
  int tid = threadIdx.x;
  int tm = tid >> 4, tn = tid & 15;
  int row0 = blockIdx.y * 64;
  int colbase = (row0 >> 10) * 64;
  int k0b = blockIdx.z * KC;
  float acc[4][4] = {{0.f}};
  for (int k0 = k0b; k0 < k0b + KC; k0 += 16) {
#pragma unroll
    for (int i = 0; i < 4; ++i) {
      int idx = tid + i * 256;
      As2[idx >> 4][idx & 15] = A[(size_t)(row0 + (idx >> 4)) * 1024 + k0 + (idx & 15)];
    }
#pragma unroll
    for (int rr = 0; rr < 4; ++rr) {
      int id2 = tid + rr * 256;
      Bs[id2 >> 6][id2 & 63] = M1[(size_t)(k0 + (id2 >> 6)) * 128 + colbase + (id2 & 63)];
    }
    __syncthreads();
#pragma unroll
    for (int kk = 0; kk < 16; ++kk) {
      float a[4], b[4];
#pragma unroll
      for (int i = 0; i < 4; ++i) a[i] = As2[tm * 4 + i][kk];
#pragma unroll
      for (int j = 0; j < 4; ++j) b[j] = Bs[kk][tn * 4 + j];
#pragma unroll
      for (int i = 0; i < 4; ++i)
#pragma unroll
        for (int j = 0; j < 4; ++j) acc[i][j] += a[i] * b[j];
    }
    __syncthreads();
  }
  float* pp = part + (size_t)blockIdx.z * 131072;
#pragma unroll
  for (int i = 0; i < 4; ++i) {
    float4 v = make_float4(acc[i][0], acc[i][1], acc[i][2], acc[i][3]);
    *(float4*)&pp[(size_t)(row0 + tm * 4 + i) * 64 + tn * 4] = v;
  }
}

// ---- wave-parallel imp-reduce + top-2: one wave per (b,s), lane = block n ----
__global__ __launch_bounds__(256) void topk_wave(const float* __restrict__ part, int* __restrict__ tk) {
  int wid = threadIdx.x >> 6, lane = threadIdx.x & 63;
  int bs = blockIdx.x * 4 + wid;
  float v = 0.f;
  const float* p = part + (size_t)bs * 64 + lane;
#pragma unroll
  for (int z = 0; z < 8; ++z) v += p[(size_t)z * 131072];
  float v1 = v; int i1 = lane;
#pragma unroll
  for (int off = 32; off; off >>= 1) {
    float ov = __shfl_xor(v1, off);
    int oi = __shfl_xor(i1, off);
    if (ov > v1 || (ov == v1 && oi < i1)) { v1 = ov; i1 = oi; }
  }
  float v2 = (lane == i1) ? -3.0e38f : v;
  int i2 = lane;
#pragma unroll
  for (int off = 32; off; off >>= 1) {
    float ov = __shfl_xor(v2, off);
    int oi = __shfl_xor(i2, off);
    if (ov > v2 || (ov == v2 && oi < i2)) { v2 = ov; i2 = oi; }
  }
  if (lane == 0) {
    tk[bs * 2] = i1;
    tk[bs * 2 + 1] = i2;
  }
}

// ---- staging helpers (fp32 ck/cv -> swizzled bf16 LDS) ----
__device__ inline void stage_rows_bf16(const float* __restrict__ src, size_t pitch,
                                       bf16* __restrict__ dst, int tid) {
  int r = tid >> 2, qq = tid & 3;
  const float4* sp = (const float4*)(src + (size_t)r * pitch) + qq * 4;
  float4 f0 = sp[0], f1 = sp[1], f2 = sp[2], f3 = sp[3];
  bf16x8 lo, hi;
  lo[0] = (bf16)f0.x; lo[1] = (bf16)f0.y; lo[2] = (bf16)f0.z; lo[3] = (bf16)f0.w;
  lo[4] = (bf16)f1.x; lo[5] = (bf16)f1.y; lo[6] = (bf16)f1.z; lo[7] = (bf16)f1.w;
  hi[0] = (bf16)f2.x; hi[1] = (bf16)f2.y; hi[2] = (bf16)f2.z; hi[3] = (bf16)f2.w;
  hi[4] = (bf16)f3.x; hi[5] = (bf16)f3.y; hi[6] = (bf16)f3.z; hi[7] = (bf16)f3.w;
  int cb = qq * 2;
  *(bf16x8*)&dst[SWZ_IDX(r, cb)]     = lo;
  *(bf16x8*)&dst[SWZ_IDX(r, cb + 1)] = hi;
}

__device__ inline void stage_cols_bf16(const float* __restrict__ src, size_t pitch,
                                       bf16* __restrict__ dst, int tid) {
  int lane = tid & 63, w = tid >> 6;
  const float4* sp = (const float4*)(src + (size_t)lane * pitch + w * 16);
  float4 f[4];
  f[0] = sp[0]; f[1] = sp[1]; f[2] = sp[2]; f[3] = sp[3];
  const float* ff = (const float*)f;
#pragma unroll
  for (int i = 0; i < 16; ++i) {
    int d = w * 16 + i;
    dst[(d << 6) + ((((lane >> 3) ^ (d & 7))) << 3) + (lane & 7)] = (bf16)ff[i];
  }
}

// ---- fused comp + window MFMA flash attention, double-buffered K/V ----
__global__ __launch_bounds__(256) void attn_mfma(const bf16* __restrict__ qbf, const bf16* __restrict__ kbf,
                                                 const bf16* __restrict__ vbf, const float* __restrict__ ck,
                                                 const float* __restrict__ cv, const float* __restrict__ gat,
                                                 const float* __restrict__ selp, bf16* __restrict__ accbf) {
  __shared__ bf16 Qs[4096];
  __shared__ bf16 Kb[2][4096];
  __shared__ bf16 Vb[2][4096];
  __shared__ bf16 Ps[4096];
  int tid = threadIdx.x, w = tid >> 6, lane = tid & 63;
  int l8 = lane >> 3, s8 = lane & 7;
  int qd = lane >> 4, l16 = lane & 15;
  int s0 = blockIdx.x * 64, h = blockIdx.y, b = blockIdx.z;
  bf16* Pw = Ps + w * 1024;

  const bf16* qsrc = qbf + ((size_t)(b * 1024 + s0)) * kD + h * 64;
#pragma unroll
  for (int i = 0; i < 2; ++i) {
    int row = w * 16 + i * 8 + l8;
    async_ld16(&qsrc[(size_t)row * kD + (s8 ^ l8) * 8], Qs + w * 1024 + i * 512);
  }
  stage_rows_bf16(ck + ((size_t)(b * 64)) * kD + h * 64, kD, Kb[0], tid);
  stage_cols_bf16(cv + ((size_t)(b * 64)) * kD + h * 64, kD, Vb[0], tid);
  __syncthreads();

  int kb0 = s0 - 256; if (kb0 < 0) kb0 = 0;
  int nck = (s0 + 64 - kb0) >> 6;

  bf16x8 pv0, pv1;
  {
    const bf16* ksrc = kbf + ((size_t)(b * 1024 + kb0)) * kD + h * 64;
#pragma unroll
    for (int i = 0; i < 2; ++i) {
      int row = w * 16 + i * 8 + l8;
      async_ld16(&ksrc[(size_t)row * kD + (s8 ^ l8) * 8], Kb[1] + w * 1024 + i * 512);
    }
    const bf16* vsrc = vbf + ((size_t)(b * 1024 + kb0 + lane)) * kD + h * 64 + w * 16;
    pv0 = *(const bf16x8*)vsrc;
    pv1 = *(const bf16x8*)(vsrc + 8);
  }

  f32x4 oc[4] = {};
  float lc[4];
  {
    f32x4 sacc[4] = {};
#pragma unroll
    for (int ks = 0; ks < 2; ++ks) {
      bf16x8 aq = LDV(Qs, w * 16 + l16, qd + 4 * ks);
#pragma unroll
      for (int j = 0; j < 4; ++j)
        sacc[j] = __builtin_amdgcn_mfma_f32_16x16x32_bf16(aq, LDV(Kb[0], 16 * j + l16, qd + 4 * ks), sacc[j], 0, 0, 0);
    }
    {
      bf16* Vt = Vb[1];
#pragma unroll
      for (int i = 0; i < 8; ++i) { int d = w * 16 + i;     Vt[(d << 6) + ((l8 ^ (d & 7)) << 3) + s8] = pv0[i]; }
#pragma unroll
      for (int i = 0; i < 8; ++i) { int d = w * 16 + 8 + i; Vt[(d << 6) + ((l8 ^ (d & 7)) << 3) + s8] = pv1[i]; }
    }
#pragma unroll
    for (int j = 0; j < 4; ++j)
#pragma unroll
      for (int r = 0; r < 4; ++r) sacc[j][r] *= kInv;
#pragma unroll
    for (int r = 0; r < 4; ++r) {
      float mx = sacc[0][r];
#pragma unroll
      for (int j = 1; j < 4; ++j) mx = fmaxf(mx, sacc[j][r]);
#pragma unroll
      for (int off = 8; off; off >>= 1) mx = fmaxf(mx, __shfl_xor(mx, off));
      int qrow = qd * 4 + r;
      float rs = 0.f;
#pragma unroll
      for (int j = 0; j < 4; ++j) {
        float e = __expf(sacc[j][r] - mx);
        int col = l16 + 16 * j;
        Pw[(qrow << 6) + ((((col >> 3) ^ (qrow & 7))) << 3) + (col & 7)] = (bf16)e;
        rs += e;
      }
#pragma unroll
      for (int off = 8; off; off >>= 1) rs += __shfl_xor(rs, off);
      lc[r] = rs;
    }
#pragma unroll
    for (int ks = 0; ks < 2; ++ks) {
      bf16x8 ap = LDV(Pw, l16, qd + 4 * ks);
#pragma unroll
      for (int j = 0; j < 4; ++j)
        oc[j] = __builtin_amdgcn_mfma_f32_16x16x32_bf16(ap, LDV(Vb[0], 16 * j + l16, qd + 4 * ks), oc[j], 0, 0, 0);
    }
  }

  f32x4 ow[4] = {};
  float mw[4], lw[4];
#pragma unroll
  for (int r = 0; r < 4; ++r) { mw[r] = -1e30f; lw[r] = 0.f; }
  for (int c = 0; c < nck; ++c) {
    int cur = (c & 1) ^ 1, oth = c & 1;
    int kbase = kb0 + c * 64;
    __syncthreads();
    if (c + 1 < nck) {
      const bf16* ksrc = kbf + ((size_t)(b * 1024 + kbase + 64)) * kD + h * 64;
#pragma unroll
      for (int i = 0; i < 2; ++i) {
        int row = w * 16 + i * 8 + l8;
        async_ld16(&ksrc[(size_t)row * kD + (s8 ^ l8) * 8], Kb[oth] + w * 1024 + i * 512);
      }
      const bf16* vsrc = vbf + ((size_t)(b * 1024 + kbase + 64 + lane)) * kD + h * 64 + w * 16;
      pv0 = *(const bf16x8*)vsrc;
      pv1 = *(const bf16x8*)(vsrc + 8);
    }
    f32x4 sacc[4] = {};
#pragma unroll
    for (int ks = 0; ks < 2; ++ks) {
      bf16x8 aq = LDV(Qs, w * 16 + l16, qd + 4 * ks);
#pragma unroll
      for (int j = 0; j < 4; ++j)
        sacc[j] = __builtin_amdgcn_mfma_f32_16x16x32_bf16(aq, LDV(Kb[cur], 16 * j + l16, qd + 4 * ks), sacc[j], 0, 0, 0);
    }
    if (c + 1 < nck) {
      bf16* Vt = Vb[oth];
#pragma unroll
      for (int i = 0; i < 8; ++i) { int d = w * 16 + i;     Vt[(d << 6) + ((l8 ^ (d & 7)) << 3) + s8] = pv0[i]; }
#pragma unroll
      for (int i = 0; i < 8; ++i) { int d = w * 16 + 8 + i; Vt[(d << 6) + ((l8 ^ (d & 7)) << 3) + s8] = pv1[i]; }
    }
#pragma unroll
    for (int j = 0; j < 4; ++j)
#pragma unroll
      for (int r = 0; r < 4; ++r) {
        int key = kbase + 16 * j + l16;
        int sq = s0 + w * 16 + qd * 4 + r;
        float sc = sacc[j][r] * kInv;
        sacc[j][r] = (key <= sq && sq - key <= 256) ? sc : -1e30f;
      }
#pragma unroll
    for (int r = 0; r < 4; ++r) {
      float mx = sacc[0][r];
#pragma unroll
      for (int j = 1; j < 4; ++j) mx = fmaxf(mx, sacc[j][r]);
#pragma unroll
      for (int off = 8; off; off >>= 1) mx = fmaxf(mx, __shfl_xor(mx, off));
      float mn = fmaxf(mw[r], mx);
      float alpha = __expf(mw[r] - mn);
      mw[r] = mn;
      int qrow = qd * 4 + r;
      float rs = 0.f;
#pragma unroll
      for (int j = 0; j < 4; ++j) {
        float e = __expf(sacc[j][r] - mn);
        int col = l16 + 16 * j;
        Pw[(qrow << 6) + ((((col >> 3) ^ (qrow & 7))) << 3) + (col & 7)] = (bf16)e;
        rs += e;
      }
#pragma unroll
      for (int off = 8; off; off >>= 1) rs += __shfl_xor(rs, off);
      lw[r] = lw[r] * alpha + rs;
#pragma unroll
      for (int j = 0; j < 4; ++j) ow[j][r] *= alpha;
    }
#pragma unroll
    for (int ks = 0; ks < 2; ++ks) {
      bf16x8 ap = LDV(Pw, l16, qd + 4 * ks);
#pragma unroll
      for (int j = 0; j < 4; ++j)
        ow[j] = __builtin_amdgcn_mfma_f32_16x16x32_bf16(ap, LDV(Vb[cur], 16 * j + l16, qd + 4 * ks), ow[j], 0, 0, 0);
    }
  }

#pragma unroll
  for (int r = 0; r < 4; ++r) {
    int sq = s0 + w * 16 + qd * 4 + r;
    size_t row = (size_t)b * 1024 + sq;
    float g0 = gat[row * 3 + 0], g2 = gat[row * 3 + 2];
    float c0 = g0 / lc[r], c2 = g2 / lw[r];
#pragma unroll
    for (int j = 0; j < 4; ++j) {
      size_t off = row * kD + h * 64 + 16 * j + l16;
      accbf[off] = (bf16)(oc[j][r] * c0 + ow[j][r] * c2 + selp[off]);
    }
  }
}

// ---- selected attention: writes selp = g1*out_sel ----
__global__ __launch_bounds__(256) void sel_attn2(const bf16* __restrict__ qbf, const bf16* __restrict__ kbf,
                                                 const bf16* __restrict__ vbf, const int* __restrict__ tk,
                                                 const float* __restrict__ gat, float* __restrict__ selp) {
  int wid = threadIdx.x >> 6, lane = threadIdx.x & 63;
  int g = blockIdx.x * 4 + wid;
  int h = g & 15, bs = g >> 4, b = bs >> 10, s = bs & 1023;
  __shared__ float qs[4][64];
  qs[wid][lane] = (float)qbf[(size_t)bs * kD + h * 64 + lane];
  __syncthreads();
  int m = lane & 15, dg = lane >> 4;
  int blk = tk[((size_t)(m >> 3) * 1024 + s) * 2 + b];
  int tok = (m >> 3) * 1024 + blk * 16 + (m & 7);
  const bf16* kp = kbf + (size_t)tok * kD + h * 64 + dg * 16;
  bf16x8 k0 = *(const bf16x8*)kp;
  bf16x8 k1 = *(const bf16x8*)(kp + 8);
  float sc = 0.f;
#pragma unroll
  for (int i = 0; i < 8; ++i) sc += (float)k0[i] * qs[wid][dg * 16 + i];
#pragma unroll
  for (int i = 0; i < 8; ++i) sc += (float)k1[i] * qs[wid][dg * 16 + 8 + i];
  sc += __shfl_xor(sc, 16);
  sc += __shfl_xor(sc, 32);
  sc *= kInv;
  float mx = sc;
#pragma unroll
  for (int off = 8; off; off >>= 1) mx = fmaxf(mx, __shfl_xor(mx, off));
  float e = __expf(sc - mx);
  float ss = e;
#pragma unroll
  for (int off = 8; off; off >>= 1) ss += __shfl_xor(ss, off);
  float p = e / ss;
  const bf16* vb = vbf + h * 64 + lane;
  float o = 0.f;
#pragma unroll
  for (int mi = 0; mi < 16; ++mi) {
    int tm = __shfl(tok, mi);
    float pm = __shfl(p, mi);
    o += pm * (float)vb[(size_t)tm * kD];
  }
  selp[(size_t)bs * kD + h * 64 + lane] = gat[bs * 3 + 1] * o;
}

// ---- bf16 MFMA GEMM core (gemm_out) ----
__device__ __forceinline__ void gemm_core(const bf16* __restrict__ A, const bf16* __restrict__ Bt,
                                          int K, int row0, int col0, bf16* As, bf16* Bs,
                                          int tid, f32x4 (&acc)[4][2]) {
  int w = tid >> 6, lane = tid & 63;
  int l8 = lane >> 3, s8 = lane & 7;
  int qd = lane >> 4, l16 = lane & 15;
  int mr = (w & 1) * 64, nc = (w >> 1) * 32;
  for (int k0 = 0; k0 < K; k0 += 64) {
    __syncthreads();
#pragma unroll
    for (int i = 0; i < 4; ++i) {
      int row = w * 32 + i * 8 + l8;
      async_ld16(&A[(size_t)(row0 + row) * K + k0 + (s8 ^ l8) * 8], As + w * 2048 + i * 512);
    }
#pragma unroll
    for (int i = 0; i < 2; ++i) {
      int row = w * 16 + i * 8 + l8;
      async_ld16(&Bt[(size_t)(col0 + row) * K + k0 + (s8 ^ l8) * 8], Bs + w * 1024 + i * 512);
    }
    __syncthreads();
#pragma unroll
    for (int ks = 0; ks < 2; ++ks) {
      bf16x8 af[4], bfr[2];
#pragma unroll
      for (int i = 0; i < 4; ++i) af[i] = LDV(As, mr + i * 16 + l16, ks * 4 + qd);
#pragma unroll
      for (int j = 0; j < 2; ++j) bfr[j] = LDV(Bs, nc + j * 16 + l16, ks * 4 + qd);
#pragma unroll
      for (int i = 0; i < 4; ++i)
#pragma unroll
        for (int j = 0; j < 2; ++j)
          acc[i][j] = __builtin_amdgcn_mfma_f32_16x16x32_bf16(af[i], bfr[j], acc[i][j], 0, 0, 0);
    }
  }
}

// ---- out = accbf@Wo + bo, fp32 out ----
__global__ __launch_bounds__(256) void gemm_out(const bf16* __restrict__ accbf, const bf16* __restrict__ Wot,
                                                float* __restrict__ out, const float* __restrict__ bo) {
  __shared__ bf16 As[128 * 64];
  __shared__ bf16 Bs[64 * 64];
  int tid = threadIdx.x;
  int row0 = blockIdx.y * 128, col0 = blockIdx.x * 64;
  f32x4 acc[4][2] = {};
  gemm_core(accbf, Wot, 1024, row0, col0, As, Bs, tid, acc);
  int w = tid >> 6, lane = tid & 63, qd = lane >> 4, l16 = lane & 15;
  int mr = (w & 1) * 64, nc = (w >> 1) * 32;
#pragma unroll
  for (int i = 0; i < 4; ++i)
#pragma unroll
    for (int j = 0; j < 2; ++j)
#pragma unroll
      for (int r = 0; r < 4; ++r) {
        int rr = row0 + mr + i * 16 + qd * 4 + r;
        int cc = col0 + nc + j * 16 + l16;
        out[(size_t)rr * kD + cc] = acc[i][j][r] + bo[cc];
      }
}

extern "C" void kernel_launch(void* const* d_in, const int* in_sizes, int n_in,
                              void* d_out, int out_size, void* d_ws, size_t ws_size,
                              hipStream_t stream) {
  const float* x   = (const float*)d_in[0];
  const float* Wq  = (const float*)d_in[1];
  const float* Wk  = (const float*)d_in[2];
  const float* Wv  = (const float*)d_in[3];
  const float* Wo  = (const float*)d_in[4];
  const float* bo  = (const float*)d_in[5];
  const float* Wg  = (const float*)d_in[6];
  const float* bg  = (const float*)d_in[7];
  const float* wkc = (const float*)d_in[8];
  const float* wvc = (const float*)d_in[9];
  const float* wpe = (const float*)d_in[10];
  float* out = (float*)d_out;

  float* ws    = (float*)d_ws;
  bf16*  qkvbf = (bf16*)ws;                    // 3 x 2097152 bf16
  float* accb  = ws + 3145728;                 // 2097152 (sel partial, fp32)
  float* ck    = accb + 2097152;               // 131072
  float* cv    = ck + 131072;
  float* cxk   = cv + 131072;
  float* cxv   = cxk + 131072;
  float* M1    = cxv + 131072;                 // [1024][128]
  float* gat   = M1 + 131072;                  // 6144
  int*   tk    = (int*)(gat + 6144);           // 4096 ints
  bf16*  xbf   = (bf16*)(gat + 6144 + 4096);   // 2097152 bf16
  bf16*  Wt4   = (bf16*)((float*)xbf + 1048576);   // 4 x 1048576 bf16
  bf16*  accbf = (bf16*)((float*)Wt4 + 2097152);   // 2097152 bf16
  float* skbuf  = (float*)accbf + 1048576;     // 16 x 131072 (ck|cv partials)
  float* skbuf2 = skbuf + 2097152;             // 8 x 131072 (M1 then imp partials)
  const bf16* qbf = qkvbf;
  const bf16* kbf = qkvbf + 2097152;
  const bf16* vbf = qkvbf + 2 * 2097152;

  prep_all<<<7680, 256, 0, stream>>>(x, wkc, wvc, Wg, bg, Wq, Wk, Wv, Wo, cxk, cxv, xbf, gat, Wt4);

  mid_fused<<<768, 256, 0, stream>>>(xbf, Wt4, qkvbf, wpe, cxk, cxv, Wk, Wv, skbuf);
  reduce_ckcv<<<256, 256, 0, stream>>>(skbuf, ck, cv, wkc, wvc, wpe);

  sgemm_nt_sk<<<dim3(2, 16, 8), 256, 0, stream>>>(Wq, ck, skbuf2, 1024, 128, 1024, 128);
  reduce_sk<<<128, 256, 0, stream>>>(skbuf2, M1, 131072, 8);
  imp_sk<<<dim3(1, 32, 8), 256, 0, stream>>>(x, M1, skbuf2, 128);
  topk_wave<<<512, 256, 0, stream>>>(skbuf2, tk);

  sel_attn2<<<8192, 256, 0, stream>>>(qbf, kbf, vbf, tk, gat, accb);
  attn_mfma<<<dim3(16, 16, 2), 256, 0, stream>>>(qbf, kbf, vbf, ck, cv, gat, accb, accbf);

  gemm_out<<<dim3(16, 16), 256, 0, stream>>>(accbf, Wt4 + (size_t)3 * 1048576, out, bo);
}

// Round 10
// 218.482 us; speedup vs baseline: 1.3946x; 1.0278x over previous
//
#include <hip/hip_runtime.h>

// NativeSparseAttention round 10: un-fuse QKV z-dim — round-9 profile showed
// mid_fused at 49 µs / MfmaUtil 8.8% / occupancy 9% because the z-fused QKV
// grid was 256 blocks = 1 block/CU. Per-z tiles -> 768 QKV + 512 ck/cv blocks
// in one mixed dispatch (5 blocks/CU), LDS 40->24 KB, QKV VGPR acc 96->32.
// B=2 S=1024 D=1024 H=KV=16 HD=64 Nc=64 CB=16 SB=8 J=2 W=256

typedef __bf16 bf16;
typedef bf16 bf16x8 __attribute__((ext_vector_type(8)));
typedef float f32x4 __attribute__((ext_vector_type(4)));

constexpr int kD = 1024;
constexpr float kInv = 0.125f;  // 1/sqrt(64)

#define SWZ_IDX(row, cb) (((row) << 6) + (((cb) ^ ((row) & 7)) << 3))
#define LDV(arr, row, cb) (*(const bf16x8*)&(arr)[SWZ_IDX(row, cb)])

__device__ __forceinline__ void async_ld16(const bf16* g, bf16* l) {
  __builtin_amdgcn_global_load_lds(
      (const __attribute__((address_space(1))) unsigned int*)g,
      (__attribute__((address_space(3))) unsigned int*)l, 16, 0, 0);
}

// ---- fused prep: [0,512) cx ; [512,1536) x->bf16 ; [1536,3584) gates ;
//      [3584,7680) transpose 4 weights -> bf16 [C][R] ----
__global__ __launch_bounds__(256) void prep_all(const float* __restrict__ x, const float* __restrict__ wkc,
                                                const float* __restrict__ wvc, const float* __restrict__ Wg,
                                                const float* __restrict__ bg, const float* __restrict__ Wq,
                                                const float* __restrict__ Wk, const float* __restrict__ Wv,
                                                const float* __restrict__ Wo, float* __restrict__ cxk,
                                                float* __restrict__ cxv, bf16* __restrict__ xbf,
                                                float* __restrict__ gates, bf16* __restrict__ Wt4) {
  __shared__ float sh[32 * 33];
  int blk = blockIdx.x, tid = threadIdx.x;
  if (blk < 512) {
    int idx = blk * 256 + tid;
    int d = idx & 1023, bn = idx >> 10;
    const float* xp = x + (size_t)bn * 16 * kD + d;
    float a = 0.f, c = 0.f;
    for (int t = 0; t < 16; ++t) {
      float xv = xp[(size_t)t * kD];
      a += wkc[t] * xv;
      c += wvc[t] * xv;
    }
    cxk[idx] = a;
    cxv[idx] = c;
  } else if (blk < 1536) {
    int i = (blk - 512) * 256 + tid;
    const float4* p = (const float4*)x + (size_t)i * 2;
    float4 a = p[0], b = p[1];
    bf16x8 v;
    v[0] = (bf16)a.x; v[1] = (bf16)a.y; v[2] = (bf16)a.z; v[3] = (bf16)a.w;
    v[4] = (bf16)b.x; v[5] = (bf16)b.y; v[6] = (bf16)b.z; v[7] = (bf16)b.w;
    *(bf16x8*)&xbf[(size_t)i * 8] = v;
  } else if (blk < 3584) {
    int bs = blk - 1536;
    float (*red)[256] = (float(*)[256])sh;
    const float* xp = x + (size_t)bs * kD;
    float p0 = 0.f, p1 = 0.f, p2 = 0.f;
    for (int d = tid; d < kD; d += 256) {
      float xv = xp[d];
      p0 += xv * Wg[d * 3 + 0];
      p1 += xv * Wg[d * 3 + 1];
      p2 += xv * Wg[d * 3 + 2];
    }
    red[0][tid] = p0; red[1][tid] = p1; red[2][tid] = p2;
    __syncthreads();
    for (int off = 128; off > 0; off >>= 1) {
      if (tid < off) {
        red[0][tid] += red[0][tid + off];
        red[1][tid] += red[1][tid + off];
        red[2][tid] += red[2][tid + off];
      }
      __syncthreads();
    }
    if (tid < 3) gates[bs * 3 + tid] = 1.f / (1.f + __expf(-(red[tid][0] + bg[tid])));
  } else {
    int t4 = blk - 3584;
    int z = t4 >> 10, rem = t4 & 1023;
    const float* in = (z == 0) ? Wq : (z == 1) ? Wk : (z == 2) ? Wv : Wo;
    bf16* outp = Wt4 + (size_t)z * 1048576;
    int c0 = (rem & 31) * 32, r0 = (rem >> 5) * 32;
    float (*t)[33] = (float(*)[33])sh;
    int tx = tid & 31, ty = tid >> 5;
#pragma unroll
    for (int i = 0; i < 32; i += 8) t[ty + i][tx] = in[(size_t)(r0 + ty + i) * 1024 + c0 + tx];
    __syncthreads();
#pragma unroll
    for (int i = 0; i < 32; i += 8) outp[(size_t)(c0 + ty + i) * 1024 + r0 + tx] = (bf16)t[tx][ty + i];
  }
}

// ---- bf16 MFMA GEMM core: BM=128 BN=64 BK=64, async swizzled LDS staging ----
__device__ __forceinline__ void gemm_core(const bf16* __restrict__ A, const bf16* __restrict__ Bt,
                                          int K, int row0, int col0, bf16* As, bf16* Bs,
                                          int tid, f32x4 (&acc)[4][2]) {
  int w = tid >> 6, lane = tid & 63;
  int l8 = lane >> 3, s8 = lane & 7;
  int qd = lane >> 4, l16 = lane & 15;
  int mr = (w & 1) * 64, nc = (w >> 1) * 32;
  for (int k0 = 0; k0 < K; k0 += 64) {
    __syncthreads();
#pragma unroll
    for (int i = 0; i < 4; ++i) {
      int row = w * 32 + i * 8 + l8;
      async_ld16(&A[(size_t)(row0 + row) * K + k0 + (s8 ^ l8) * 8], As + w * 2048 + i * 512);
    }
#pragma unroll
    for (int i = 0; i < 2; ++i) {
      int row = w * 16 + i * 8 + l8;
      async_ld16(&Bt[(size_t)(col0 + row) * K + k0 + (s8 ^ l8) * 8], Bs + w * 1024 + i * 512);
    }
    __syncthreads();
#pragma unroll
    for (int ks = 0; ks < 2; ++ks) {
      bf16x8 af[4], bfr[2];
#pragma unroll
      for (int i = 0; i < 4; ++i) af[i] = LDV(As, mr + i * 16 + l16, ks * 4 + qd);
#pragma unroll
      for (int j = 0; j < 2; ++j) bfr[j] = LDV(Bs, nc + j * 16 + l16, ks * 4 + qd);
#pragma unroll
      for (int i = 0; i < 4; ++i)
#pragma unroll
        for (int j = 0; j < 2; ++j)
          acc[i][j] = __builtin_amdgcn_mfma_f32_16x16x32_bf16(af[i], bfr[j], acc[i][j], 0, 0, 0);
    }
  }
}

// ---- fused mid: blocks [0,768) per-z QKV MFMA GEMM (z = blk/256, 128x64 tile);
// [768,1280) fp32 split-K ck|cv partials. 1280 blocks = 5/CU, mixed pipes.
__global__ __launch_bounds__(256) void mid_fused(const bf16* __restrict__ xbf, const bf16* __restrict__ Wt4,
                                                 bf16* __restrict__ qkv, const float* __restrict__ wpe,
                                                 const float* __restrict__ cxk, const float* __restrict__ cxv,
                                                 const float* __restrict__ Wk, const float* __restrict__ Wv,
                                                 float* __restrict__ part) {
  __shared__ __align__(16) char smem[24576];
  int tid = threadIdx.x;
  if (blockIdx.x < 768) {
    // ---- QKV per-z: 128x64 tile, grid 3 x 256 ----
    bf16* As = (bf16*)smem;             // 128*64*2 = 16 KB
    bf16* Bs = (bf16*)(smem + 16384);   // 64*64*2  =  8 KB
    int z = blockIdx.x >> 8, t = blockIdx.x & 255;
    int row0 = (t >> 4) * 128, col0 = (t & 15) * 64;
    f32x4 acc[4][2] = {};
    gemm_core(xbf, Wt4 + (size_t)z * 1048576, 1024, row0, col0, As, Bs, tid, acc);
    int w = tid >> 6, lane = tid & 63, qd = lane >> 4, l16 = lane & 15;
    int mr = (w & 1) * 64, nc = (w >> 1) * 32;
    bf16* C = qkv + (size_t)z * 2097152;
#pragma unroll
    for (int i = 0; i < 4; ++i)
#pragma unroll
      for (int j = 0; j < 2; ++j)
#pragma unroll
        for (int r = 0; r < 4; ++r) {
          int rr = row0 + mr + i * 16 + qd * 4 + r;
          int cc = col0 + nc + j * 16 + l16;
          float v = acc[i][j][r];
          if (z) v += wpe[(rr & 15) * kD + cc];
          C[(size_t)rr * kD + cc] = (bf16)v;
        }
  } else {
    // ---- ck|cv split-K fp32 partials: z<8 -> cxk@Wk, z>=8 -> cxv@Wv ----
    float (*As2)[17] = (float(*)[17])smem;            // 64x17
    float (*Bs)[68] = (float(*)[68])(smem + 4352);    // 16x68
    int t = blockIdx.x - 768;
    int z = t >> 5, rem = t & 31;
    const float* A = (z < 8) ? cxk : cxv;
    const float* Bm = (z < 8) ? Wk : Wv;
    int tm = tid >> 4, tn = tid & 15;
    int row0 = (rem >> 4) * 64, col0 = (rem & 15) * 64;
    int k0b = (z & 7) * 128;
    float acc[4][4] = {{0.f}};
    for (int k0 = k0b; k0 < k0b + 128; k0 += 16) {
#pragma unroll
      for (int i = 0; i < 4; ++i) {
        int idx = tid + i * 256;
        As2[idx >> 4][idx & 15] = A[(size_t)(row0 + (idx >> 4)) * 1024 + k0 + (idx & 15)];
        Bs[idx >> 6][idx & 63] = Bm[(size_t)(k0 + (idx >> 6)) * 1024 + col0 + (idx & 63)];
      }
      __syncthreads();
#pragma unroll
      for (int kk = 0; kk < 16; ++kk) {
        float a[4], b[4];
#pragma unroll
        for (int i = 0; i < 4; ++i) a[i] = As2[tm * 4 + i][kk];
#pragma unroll
        for (int j = 0; j < 4; ++j) b[j] = Bs[kk][tn * 4 + j];
#pragma unroll
        for (int i = 0; i < 4; ++i)
#pragma unroll
          for (int j = 0; j < 4; ++j) acc[i][j] += a[i] * b[j];
      }
      __syncthreads();
    }
    float* pp = part + (size_t)z * 131072;
#pragma unroll
    for (int i = 0; i < 4; ++i) {
      float4 v = make_float4(acc[i][0], acc[i][1], acc[i][2], acc[i][3]);
      *(float4*)&pp[(size_t)(row0 + tm * 4 + i) * 1024 + col0 + tn * 4] = v;
    }
  }
}

// ---- reduce ck|cv partials with inline cpe ----
__global__ __launch_bounds__(256) void reduce_ckcv(const float* __restrict__ part, float* __restrict__ ck,
                                                   float* __restrict__ cv, const float* __restrict__ wkc,
                                                   const float* __restrict__ wvc, const float* __restrict__ wpe) {
  int half = blockIdx.x >> 7;
  int i4 = (((blockIdx.x & 127) * 256) + threadIdx.x) * 4;
  const float* pp = part + (size_t)half * 8 * 131072;
  float4 s = *(const float4*)&pp[i4];
  for (int z = 1; z < 8; ++z) {
    float4 p = *(const float4*)&pp[(size_t)z * 131072 + i4];
    s.x += p.x; s.y += p.y; s.z += p.z; s.w += p.w;
  }
  int c = i4 & 1023;
  const float* w = half ? wvc : wkc;
  float e0 = 0.f, e1 = 0.f, e2 = 0.f, e3 = 0.f;
  for (int t = 0; t < 16; ++t) {
    float wt = w[t];
    const float* pe = wpe + t * 1024 + c;
    e0 += wt * pe[0]; e1 += wt * pe[1]; e2 += wt * pe[2]; e3 += wt * pe[3];
  }
  s.x += e0; s.y += e1; s.z += e2; s.w += e3;
  float* dst = half ? cv : ck;
  *(float4*)&dst[i4] = s;
}

// ---- split-K fp32 NT GEMM: M1 partials (imp path, fp32-exact) ----
__global__ __launch_bounds__(256) void sgemm_nt_sk(const float* __restrict__ A, const float* __restrict__ Bt,
                                                   float* __restrict__ part, int M, int N, int K, int KC) {
  __shared__ float As2[64][17];
  __shared__ float Bs2[64][17];
  int tid = threadIdx.x;
  int tm = tid >> 4, tn = tid & 15;
  int row0 = blockIdx.y * 64, col0 = blockIdx.x * 64;
  int k0b = blockIdx.z * KC;
  float acc[4][4] = {{0.f}};
  for (int k0 = k0b; k0 < k0b + KC; k0 += 16) {
#pragma unroll
    for (int i = 0; i < 4; ++i) {
      int idx = tid + i * 256;
      As2[idx >> 4][idx & 15] = A[(size_t)(row0 + (idx >> 4)) * K + k0 + (idx & 15)];
      Bs2[idx >> 4][idx & 15] = Bt[(size_t)(col0 + (idx >> 4)) * K + k0 + (idx & 15)];
    }
    __syncthreads();
#pragma unroll
    for (int kk = 0; kk < 16; ++kk) {
      float a[4], b[4];
#pragma unroll
      for (int i = 0; i < 4; ++i) a[i] = As2[tm * 4 + i][kk];
#pragma unroll
      for (int j = 0; j < 4; ++j) b[j] = Bs2[tn * 4 + j][kk];
#pragma unroll
      for (int i = 0; i < 4; ++i)
#pragma unroll
        for (int j = 0; j < 4; ++j) acc[i][j] += a[i] * b[j];
    }
    __syncthreads();
  }
  float* pp = part + (size_t)blockIdx.z * M * N;
#pragma unroll
  for (int i = 0; i < 4; ++i) {
    float4 v = make_float4(acc[i][0], acc[i][1], acc[i][2], acc[i][3]);
    *(float4*)&pp[(size_t)(row0 + tm * 4 + i) * N + col0 + tn * 4] = v;
  }
}

// ---- generic split-K reduce (M1) ----
__global__ __launch_bounds__(256) void reduce_sk(const float* __restrict__ part, float* __restrict__ C,
                                                 int total, int SK) {
  int i4 = (blockIdx.x * 256 + threadIdx.x) * 4;
  float4 s = *(const float4*)&part[i4];
  for (int z = 1; z < SK; ++z) {
    float4 p = *(const float4*)&part[(size_t)z * total + i4];
    s.x += p.x; s.y += p.y; s.z += p.z; s.w += p.w;
  }
  *(float4*)&C[i4] = s;
}

// ---- split-K imp partials ----
__global__ __launch_bounds__(256) void imp_sk(const float* __restrict__ A, const float* __restrict__ M1,
                                              float* __restrict__ part, int KC) {
  __shared__ float As2[64][17];
  __shared__ float Bs[16][68];
  int tid = threadIdx.x;
  int tm = tid >> 4, tn = tid & 15;
  int row0 = blockIdx.y * 64;
  int colbase = (row0 >> 10) * 64;
  int k0b = blockIdx.z * KC;
  float acc[4][4] = {{0.f}};
  for (int k0 = k0b; k0 < k0b + KC; k0 += 16) {
#pragma unroll
    for (int i = 0; i < 4; ++i) {
      int idx = tid + i * 256;
      As2[idx >> 4][idx & 15] = A[(size_t)(row0 + (idx >> 4)) * 1024 + k0 + (idx & 15)];
    }
#pragma unroll
    for (int rr = 0; rr < 4; ++rr) {
      int id2 = tid + rr * 256;
      Bs[id2 >> 6][id2 & 63] = M1[(size_t)(k0 + (id2 >> 6)) * 128 + colbase + (id2 & 63)];
    }
    __syncthreads();
#pragma unroll
    for (int kk = 0; kk < 16; ++kk) {
      float a[4], b[4];
#pragma unroll
      for (int i = 0; i < 4; ++i) a[i] = As2[tm * 4 + i][kk];
#pragma unroll
      for (int j = 0; j < 4; ++j) b[j] = Bs[kk][tn * 4 + j];
#pragma unroll
      for (int i = 0; i < 4; ++i)
#pragma unroll
        for (int j = 0; j < 4; ++j) acc[i][j] += a[i] * b[j];
    }
    __syncthreads();
  }
  float* pp = part + (size_t)blockIdx.z * 131072;
#pragma unroll
  for (int i = 0; i < 4; ++i) {
    float4 v = make_float4(acc[i][0], acc[i][1], acc[i][2], acc[i][3]);
    *(float4*)&pp[(size_t)(row0 + tm * 4 + i) * 64 + tn * 4] = v;
  }
}

// ---- wave-parallel imp-reduce + top-2: one wave per (b,s), lane = block n ----
__global__ __launch_bounds__(256) void topk_wave(const float* __restrict__ part, int* __restrict__ tk) {
  int wid = threadIdx.x >> 6, lane = threadIdx.x & 63;
  int bs = blockIdx.x * 4 + wid;
  float v = 0.f;
  const float* p = part + (size_t)bs * 64 + lane;
#pragma unroll
  for (int z = 0; z < 8; ++z) v += p[(size_t)z * 131072];
  float v1 = v; int i1 = lane;
#pragma unroll
  for (int off = 32; off; off >>= 1) {
    float ov = __shfl_xor(v1, off);
    int oi = __shfl_xor(i1, off);
    if (ov > v1 || (ov == v1 && oi < i1)) { v1 = ov; i1 = oi; }
  }
  float v2 = (lane == i1) ? -3.0e38f : v;
  int i2 = lane;
#pragma unroll
  for (int off = 32; off; off >>= 1) {
    float ov = __shfl_xor(v2, off);
    int oi = __shfl_xor(i2, off);
    if (ov > v2 || (ov == v2 && oi < i2)) { v2 = ov; i2 = oi; }
  }
  if (lane == 0) {
    tk[bs * 2] = i1;
    tk[bs * 2 + 1] = i2;
  }
}

// ---- staging helpers (fp32 ck/cv -> swizzled bf16 LDS) ----
__device__ inline void stage_rows_bf16(const float* __restrict__ src, size_t pitch,
                                       bf16* __restrict__ dst, int tid) {
  int r = tid >> 2, qq = tid & 3;
  const float4* sp = (const float4*)(src + (size_t)r * pitch) + qq * 4;
  float4 f0 = sp[0], f1 = sp[1], f2 = sp[2], f3 = sp[3];
  bf16x8 lo, hi;
  lo[0] = (bf16)f0.x; lo[1] = (bf16)f0.y; lo[2] = (bf16)f0.z; lo[3] = (bf16)f0.w;
  lo[4] = (bf16)f1.x; lo[5] = (bf16)f1.y; lo[6] = (bf16)f1.z; lo[7] = (bf16)f1.w;
  hi[0] = (bf16)f2.x; hi[1] = (bf16)f2.y; hi[2] = (bf16)f2.z; hi[3] = (bf16)f2.w;
  hi[4] = (bf16)f3.x; hi[5] = (bf16)f3.y; hi[6] = (bf16)f3.z; hi[7] = (bf16)f3.w;
  int cb = qq * 2;
  *(bf16x8*)&dst[SWZ_IDX(r, cb)]     = lo;
  *(bf16x8*)&dst[SWZ_IDX(r, cb + 1)] = hi;
}

__device__ inline void stage_cols_bf16(const float* __restrict__ src, size_t pitch,
                                       bf16* __restrict__ dst, int tid) {
  int lane = tid & 63, w = tid >> 6;
  const float4* sp = (const float4*)(src + (size_t)lane * pitch + w * 16);
  float4 f[4];
  f[0] = sp[0]; f[1] = sp[1]; f[2] = sp[2]; f[3] = sp[3];
  const float* ff = (const float*)f;
#pragma unroll
  for (int i = 0; i < 16; ++i) {
    int d = w * 16 + i;
    dst[(d << 6) + ((((lane >> 3) ^ (d & 7))) << 3) + (lane & 7)] = (bf16)ff[i];
  }
}

// ---- fused comp + window MFMA flash attention, double-buffered K/V ----
__global__ __launch_bounds__(256) void attn_mfma(const bf16* __restrict__ qbf, const bf16* __restrict__ kbf,
                                                 const bf16* __restrict__ vbf, const float* __restrict__ ck,
                                                 const float* __restrict__ cv, const float* __restrict__ gat,
                                                 const float* __restrict__ selp, bf16* __restrict__ accbf) {
  __shared__ bf16 Qs[4096];
  __shared__ bf16 Kb[2][4096];
  __shared__ bf16 Vb[2][4096];
  __shared__ bf16 Ps[4096];
  int tid = threadIdx.x, w = tid >> 6, lane = tid & 63;
  int l8 = lane >> 3, s8 = lane & 7;
  int qd = lane >> 4, l16 = lane & 15;
  int s0 = blockIdx.x * 64, h = blockIdx.y, b = blockIdx.z;
  bf16* Pw = Ps + w * 1024;

  const bf16* qsrc = qbf + ((size_t)(b * 1024 + s0)) * kD + h * 64;
#pragma unroll
  for (int i = 0; i < 2; ++i) {
    int row = w * 16 + i * 8 + l8;
    async_ld16(&qsrc[(size_t)row * kD + (s8 ^ l8) * 8], Qs + w * 1024 + i * 512);
  }
  stage_rows_bf16(ck + ((size_t)(b * 64)) * kD + h * 64, kD, Kb[0], tid);
  stage_cols_bf16(cv + ((size_t)(b * 64)) * kD + h * 64, kD, Vb[0], tid);
  __syncthreads();

  int kb0 = s0 - 256; if (kb0 < 0) kb0 = 0;
  int nck = (s0 + 64 - kb0) >> 6;

  bf16x8 pv0, pv1;
  {
    const bf16* ksrc = kbf + ((size_t)(b * 1024 + kb0)) * kD + h * 64;
#pragma unroll
    for (int i = 0; i < 2; ++i) {
      int row = w * 16 + i * 8 + l8;
      async_ld16(&ksrc[(size_t)row * kD + (s8 ^ l8) * 8], Kb[1] + w * 1024 + i * 512);
    }
    const bf16* vsrc = vbf + ((size_t)(b * 1024 + kb0 + lane)) * kD + h * 64 + w * 16;
    pv0 = *(const bf16x8*)vsrc;
    pv1 = *(const bf16x8*)(vsrc + 8);
  }

  f32x4 oc[4] = {};
  float lc[4];
  {
    f32x4 sacc[4] = {};
#pragma unroll
    for (int ks = 0; ks < 2; ++ks) {
      bf16x8 aq = LDV(Qs, w * 16 + l16, qd + 4 * ks);
#pragma unroll
      for (int j = 0; j < 4; ++j)
        sacc[j] = __builtin_amdgcn_mfma_f32_16x16x32_bf16(aq, LDV(Kb[0], 16 * j + l16, qd + 4 * ks), sacc[j], 0, 0, 0);
    }
    {
      bf16* Vt = Vb[1];
#pragma unroll
      for (int i = 0; i < 8; ++i) { int d = w * 16 + i;     Vt[(d << 6) + ((l8 ^ (d & 7)) << 3) + s8] = pv0[i]; }
#pragma unroll
      for (int i = 0; i < 8; ++i) { int d = w * 16 + 8 + i; Vt[(d << 6) + ((l8 ^ (d & 7)) << 3) + s8] = pv1[i]; }
    }
#pragma unroll
    for (int j = 0; j < 4; ++j)
#pragma unroll
      for (int r = 0; r < 4; ++r) sacc[j][r] *= kInv;
#pragma unroll
    for (int r = 0; r < 4; ++r) {
      float mx = sacc[0][r];
#pragma unroll
      for (int j = 1; j < 4; ++j) mx = fmaxf(mx, sacc[j][r]);
#pragma unroll
      for (int off = 8; off; off >>= 1) mx = fmaxf(mx, __shfl_xor(mx, off));
      int qrow = qd * 4 + r;
      float rs = 0.f;
#pragma unroll
      for (int j = 0; j < 4; ++j) {
        float e = __expf(sacc[j][r] - mx);
        int col = l16 + 16 * j;
        Pw[(qrow << 6) + ((((col >> 3) ^ (qrow & 7))) << 3) + (col & 7)] = (bf16)e;
        rs += e;
      }
#pragma unroll
      for (int off = 8; off; off >>= 1) rs += __shfl_xor(rs, off);
      lc[r] = rs;
    }
#pragma unroll
    for (int ks = 0; ks < 2; ++ks) {
      bf16x8 ap = LDV(Pw, l16, qd + 4 * ks);
#pragma unroll
      for (int j = 0; j < 4; ++j)
        oc[j] = __builtin_amdgcn_mfma_f32_16x16x32_bf16(ap, LDV(Vb[0], 16 * j + l16, qd + 4 * ks), oc[j], 0, 0, 0);
    }
  }

  f32x4 ow[4] = {};
  float mw[4], lw[4];
#pragma unroll
  for (int r = 0; r < 4; ++r) { mw[r] = -1e30f; lw[r] = 0.f; }
  for (int c = 0; c < nck; ++c) {
    int cur = (c & 1) ^ 1, oth = c & 1;
    int kbase = kb0 + c * 64;
    __syncthreads();
    if (c + 1 < nck) {
      const bf16* ksrc = kbf + ((size_t)(b * 1024 + kbase + 64)) * kD + h * 64;
#pragma unroll
      for (int i = 0; i < 2; ++i) {
        int row = w * 16 + i * 8 + l8;
        async_ld16(&ksrc[(size_t)row * kD + (s8 ^ l8) * 8], Kb[oth] + w * 1024 + i * 512);
      }
      const bf16* vsrc = vbf + ((size_t)(b * 1024 + kbase + 64 + lane)) * kD + h * 64 + w * 16;
      pv0 = *(const bf16x8*)vsrc;
      pv1 = *(const bf16x8*)(vsrc + 8);
    }
    f32x4 sacc[4] = {};
#pragma unroll
    for (int ks = 0; ks < 2; ++ks) {
      bf16x8 aq = LDV(Qs, w * 16 + l16, qd + 4 * ks);
#pragma unroll
      for (int j = 0; j < 4; ++j)
        sacc[j] = __builtin_amdgcn_mfma_f32_16x16x32_bf16(aq, LDV(Kb[cur], 16 * j + l16, qd + 4 * ks), sacc[j], 0, 0, 0);
    }
    if (c + 1 < nck) {
      bf16* Vt = Vb[oth];
#pragma unroll
      for (int i = 0; i < 8; ++i) { int d = w * 16 + i;     Vt[(d << 6) + ((l8 ^ (d & 7)) << 3) + s8] = pv0[i]; }
#pragma unroll
      for (int i = 0; i < 8; ++i) { int d = w * 16 + 8 + i; Vt[(d << 6) + ((l8 ^ (d & 7)) << 3) + s8] = pv1[i]; }
    }
#pragma unroll
    for (int j = 0; j < 4; ++j)
#pragma unroll
      for (int r = 0; r < 4; ++r) {
        int key = kbase + 16 * j + l16;
        int sq = s0 + w * 16 + qd * 4 + r;
        float sc = sacc[j][r] * kInv;
        sacc[j][r] = (key <= sq && sq - key <= 256) ? sc : -1e30f;
      }
#pragma unroll
    for (int r = 0; r < 4; ++r) {
      float mx = sacc[0][r];
#pragma unroll
      for (int j = 1; j < 4; ++j) mx = fmaxf(mx, sacc[j][r]);
#pragma unroll
      for (int off = 8; off; off >>= 1) mx = fmaxf(mx, __shfl_xor(mx, off));
      float mn = fmaxf(mw[r], mx);
      float alpha = __expf(mw[r] - mn);
      mw[r] = mn;
      int qrow = qd * 4 + r;
      float rs = 0.f;
#pragma unroll
      for (int j = 0; j < 4; ++j) {
        float e = __expf(sacc[j][r] - mn);
        int col = l16 + 16 * j;
        Pw[(qrow << 6) + ((((col >> 3) ^ (qrow & 7))) << 3) + (col & 7)] = (bf16)e;
        rs += e;
      }
#pragma unroll
      for (int off = 8; off; off >>= 1) rs += __shfl_xor(rs, off);
      lw[r] = lw[r] * alpha + rs;
#pragma unroll
      for (int j = 0; j < 4; ++j) ow[j][r] *= alpha;
    }
#pragma unroll
    for (int ks = 0; ks < 2; ++ks) {
      bf16x8 ap = LDV(Pw, l16, qd + 4 * ks);
#pragma unroll
      for (int j = 0; j < 4; ++j)
        ow[j] = __builtin_amdgcn_mfma_f32_16x16x32_bf16(ap, LDV(Vb[cur], 16 * j + l16, qd + 4 * ks), ow[j], 0, 0, 0);
    }
  }

#pragma unroll
  for (int r = 0; r < 4; ++r) {
    int sq = s0 + w * 16 + qd * 4 + r;
    size_t row = (size_t)b * 1024 + sq;
    float g0 = gat[row * 3 + 0], g2 = gat[row * 3 + 2];
    float c0 = g0 / lc[r], c2 = g2 / lw[r];
#pragma unroll
    for (int j = 0; j < 4; ++j) {
      size_t off = row * kD + h * 64 + 16 * j + l16;
      accbf[off] = (bf16)(oc[j][r] * c0 + ow[j][r] * c2 + selp[off]);
    }
  }
}

// ---- selected attention: writes selp = g1*out_sel ----
__global__ __launch_bounds__(256) void sel_attn2(const bf16* __restrict__ qbf, const bf16* __restrict__ kbf,
                                                 const bf16* __restrict__ vbf, const int* __restrict__ tk,
                                                 const float* __restrict__ gat, float* __restrict__ selp) {
  int wid = threadIdx.x >> 6, lane = threadIdx.x & 63;
  int g = blockIdx.x * 4 + wid;
  int h = g & 15, bs = g >> 4, b = bs >> 10, s = bs & 1023;
  __shared__ float qs[4][64];
  qs[wid][lane] = (float)qbf[(size_t)bs * kD + h * 64 + lane];
  __syncthreads();
  int m = lane & 15, dg = lane >> 4;
  int blk = tk[((size_t)(m >> 3) * 1024 + s) * 2 + b];
  int tok = (m >> 3) * 1024 + blk * 16 + (m & 7);
  const bf16* kp = kbf + (size_t)tok * kD + h * 64 + dg * 16;
  bf16x8 k0 = *(const bf16x8*)kp;
  bf16x8 k1 = *(const bf16x8*)(kp + 8);
  float sc = 0.f;
#pragma unroll
  for (int i = 0; i < 8; ++i) sc += (float)k0[i] * qs[wid][dg * 16 + i];
#pragma unroll
  for (int i = 0; i < 8; ++i) sc += (float)k1[i] * qs[wid][dg * 16 + 8 + i];
  sc += __shfl_xor(sc, 16);
  sc += __shfl_xor(sc, 32);
  sc *= kInv;
  float mx = sc;
#pragma unroll
  for (int off = 8; off; off >>= 1) mx = fmaxf(mx, __shfl_xor(mx, off));
  float e = __expf(sc - mx);
  float ss = e;
#pragma unroll
  for (int off = 8; off; off >>= 1) ss += __shfl_xor(ss, off);
  float p = e / ss;
  const bf16* vb = vbf + h * 64 + lane;
  float o = 0.f;
#pragma unroll
  for (int mi = 0; mi < 16; ++mi) {
    int tm = __shfl(tok, mi);
    float pm = __shfl(p, mi);
    o += pm * (float)vb[(size_t)tm * kD];
  }
  selp[(size_t)bs * kD + h * 64 + lane] = gat[bs * 3 + 1] * o;
}

// ---- out = accbf@Wo + bo, fp32 out ----
__global__ __launch_bounds__(256) void gemm_out(const bf16* __restrict__ accbf, const bf16* __restrict__ Wot,
                                                float* __restrict__ out, const float* __restrict__ bo) {
  __shared__ bf16 As[128 * 64];
  __shared__ bf16 Bs[64 * 64];
  int tid = threadIdx.x;
  int row0 = blockIdx.y * 128, col0 = blockIdx.x * 64;
  f32x4 acc[4][2] = {};
  gemm_core(accbf, Wot, 1024, row0, col0, As, Bs, tid, acc);
  int w = tid >> 6, lane = tid & 63, qd = lane >> 4, l16 = lane & 15;
  int mr = (w & 1) * 64, nc = (w >> 1) * 32;
#pragma unroll
  for (int i = 0; i < 4; ++i)
#pragma unroll
    for (int j = 0; j < 2; ++j)
#pragma unroll
      for (int r = 0; r < 4; ++r) {
        int rr = row0 + mr + i * 16 + qd * 4 + r;
        int cc = col0 + nc + j * 16 + l16;
        out[(size_t)rr * kD + cc] = acc[i][j][r] + bo[cc];
      }
}

extern "C" void kernel_launch(void* const* d_in, const int* in_sizes, int n_in,
                              void* d_out, int out_size, void* d_ws, size_t ws_size,
                              hipStream_t stream) {
  const float* x   = (const float*)d_in[0];
  const float* Wq  = (const float*)d_in[1];
  const float* Wk  = (const float*)d_in[2];
  const float* Wv  = (const float*)d_in[3];
  const float* Wo  = (const float*)d_in[4];
  const float* bo  = (const float*)d_in[5];
  const float* Wg  = (const float*)d_in[6];
  const float* bg  = (const float*)d_in[7];
  const float* wkc = (const float*)d_in[8];
  const float* wvc = (const float*)d_in[9];
  const float* wpe = (const float*)d_in[10];
  float* out = (float*)d_out;

  float* ws    = (float*)d_ws;
  bf16*  qkvbf = (bf16*)ws;                    // 3 x 2097152 bf16
  float* accb  = ws + 3145728;                 // 2097152 (sel partial, fp32)
  float* ck    = accb + 2097152;               // 131072
  float* cv    = ck + 131072;
  float* cxk   = cv + 131072;
  float* cxv   = cxk + 131072;
  float* M1    = cxv + 131072;                 // [1024][128]
  float* gat   = M1 + 131072;                  // 6144
  int*   tk    = (int*)(gat + 6144);           // 4096 ints
  bf16*  xbf   = (bf16*)(gat + 6144 + 4096);   // 2097152 bf16
  bf16*  Wt4   = (bf16*)((float*)xbf + 1048576);   // 4 x 1048576 bf16
  bf16*  accbf = (bf16*)((float*)Wt4 + 2097152);   // 2097152 bf16
  float* skbuf  = (float*)accbf + 1048576;     // 16 x 131072 (ck|cv partials)
  float* skbuf2 = skbuf + 2097152;             // 8 x 131072 (M1 then imp partials)
  const bf16* qbf = qkvbf;
  const bf16* kbf = qkvbf + 2097152;
  const bf16* vbf = qkvbf + 2 * 2097152;

  prep_all<<<7680, 256, 0, stream>>>(x, wkc, wvc, Wg, bg, Wq, Wk, Wv, Wo, cxk, cxv, xbf, gat, Wt4);

  mid_fused<<<1280, 256, 0, stream>>>(xbf, Wt4, qkvbf, wpe, cxk, cxv, Wk, Wv, skbuf);
  reduce_ckcv<<<256, 256, 0, stream>>>(skbuf, ck, cv, wkc, wvc, wpe);

  sgemm_nt_sk<<<dim3(2, 16, 8), 256, 0, stream>>>(Wq, ck, skbuf2, 1024, 128, 1024, 128);
  reduce_sk<<<128, 256, 0, stream>>>(skbuf2, M1, 131072, 8);
  imp_sk<<<dim3(1, 32, 8), 256, 0, stream>>>(x, M1, skbuf2, 128);
  topk_wave<<<512, 256, 0, stream>>>(skbuf2, tk);

  sel_attn2<<<8192, 256, 0, stream>>>(qbf, kbf, vbf, tk, gat, accb);
  attn_mfma<<<dim3(16, 16, 2), 256, 0, stream>>>(qbf, kbf, vbf, ck, cv, gat, accb, accbf);

  gemm_out<<<dim3(16, 16), 256, 0, stream>>>(accbf, Wt4 + (size_t)3 * 1048576, out, bo);
}